// Round 10
// baseline (227.519 us; speedup 1.0000x reference)
//
#include <hip/hip_runtime.h>
#include <hip/hip_bf16.h>

typedef __hip_bfloat16 bf16;
typedef __attribute__((ext_vector_type(8))) short s8b;   // 8 bf16 (4 VGPR)
typedef __attribute__((ext_vector_type(4))) float f4;    // MFMA C/D
typedef __attribute__((ext_vector_type(8))) unsigned short us8;

#define B_ 2
#define TIN_ 12
#define N_ 800
#define F_ 2
#define H_ 6
#define D_ 8
#define C_ 48
#define TP_ 10
#define KW_ 14
#define SCALE 0.35355339059327373f  // 1/sqrt(8)
#define LOG2E 1.4426950408889634f

__device__ __forceinline__ float sigm(float x) { return 1.0f / (1.0f + __expf(-x)); }
__device__ __forceinline__ float tanh_(float x) {
  float e = __expf(-2.0f * x);
  return 2.0f / (1.0f + e) - 1.0f;
}
__device__ __forceinline__ float exp2_(float x) { return __builtin_amdgcn_exp2f(x); }
__device__ __forceinline__ float bfu(unsigned short u) {
  return __uint_as_float((unsigned)u << 16);
}
__device__ __forceinline__ unsigned short f2u(float v) {
  return __bfloat16_as_ushort(__float2bfloat16(v));
}
__device__ __forceinline__ float ldc(const float* p, size_t i) { return p[i]; }
__device__ __forceinline__ float ldc(const bf16* p, size_t i) { return __bfloat162float(p[i]); }
__device__ __forceinline__ void ld4(const float* p, size_t i, float o[4]) {
  float4 v = *(const float4*)(p + i);
  o[0] = v.x; o[1] = v.y; o[2] = v.z; o[3] = v.w;
}
__device__ __forceinline__ void ld4(const bf16* p, size_t i, float o[4]) {
  ushort4 v = *(const ushort4*)((const unsigned short*)p + i);
  o[0] = bfu(v.x); o[1] = bfu(v.y); o[2] = bfu(v.z); o[3] = bfu(v.w);
}
__device__ __forceinline__ void sto(float* p, size_t i, float v) { p[i] = v; }
__device__ __forceinline__ void sto(bf16* p, size_t i, float v) { p[i] = __float2bfloat16(v); }

// ---------------- Kernel 0: dtype detector --------------------------------
__global__ void k_detect(const unsigned int* __restrict__ xw, int* __restrict__ flag) {
  int lane = threadIdx.x;  // 64
  unsigned int w = xw[lane];
  int e = (w >> 7) & 0xFF;  // exponent of LOW bf16 slot
  int bad = ((e >= 1 && e < 96) || (e > 150)) ? 1 : 0;
  unsigned long long m = __ballot(bad);
  if (lane == 0) *flag = (__popcll(m) >= 16) ? 1 : 0;
}

// ---------------- Kernel P: pack recurrent weights to MFMA B-fragments ----
template <typename TI>
__device__ __forceinline__ void pack_body(
    const TI* xwz, const TI* xwr, const TI* xwh,
    const TI* lwz, const TI* lwr, const TI* lwh, bf16* pwb) {
  int gid = blockIdx.x * 256 + threadIdx.x;
  const int total = 21 * 27648;
  if (gid >= total) return;
  int step = gid / 27648, r = gid % 27648;
  int g = r / 9216;  r %= 9216;
  int nt = r / 3072; r %= 3072;
  int c = r / 1536;  r %= 1536;
  int lane = r / 8, j = r % 8;
  int k = 32 * c + (lane >> 4) * 8 + j;
  int n = nt * 16 + (lane & 15);
  float v = 0.f;
  if (k < 48) {
    if (step < 11) {
      int t = step + 1;
      const TI* w = (g == 0) ? xwz : (g == 1) ? xwr : xwh;
      v = ldc(w, ((size_t)t * 144 + 96 + k) * 48 + n);
    } else {
      int t = step - 11;
      const TI* w = (g == 0) ? lwz : (g == 1) ? lwr : lwh;
      v = ldc(w, ((size_t)t * 96 + 48 + k) * 48 + n);
    }
  }
  pwb[gid] = __float2bfloat16(v);
}
__global__ void k_pack(const int* dtf, const void* xwz, const void* xwr, const void* xwh,
                       const void* lwz, const void* lwr, const void* lwh, bf16* pwb) {
  if (*dtf)
    pack_body<float>((const float*)xwz, (const float*)xwr, (const float*)xwh,
                     (const float*)lwz, (const float*)lwr, (const float*)lwh, pwb);
  else
    pack_body<bf16>((const bf16*)xwz, (const bf16*)xwr, (const bf16*)xwh,
                    (const bf16*)lwz, (const bf16*)lwr, (const bf16*)lwh, pwb);
}

// ---------------- Kernel A: temporal causal attention (t=1..11) -----------
template <typename TI>
__device__ __forceinline__ void temporal_body(
    const TI* x, const TI* Wq, const TI* Wk, const TI* Wv,
    const TI* bq, const TI* bk, const TI* bv, bf16* att_t) {
  int gid = blockIdx.x * blockDim.x + threadIdx.x;
  const int total = B_ * (TIN_ - 1) * H_ * N_;
  if (gid >= total) return;
  int n = gid % N_;
  int r = gid / N_;
  int h = r % H_;  r /= H_;
  int t = (r % (TIN_ - 1)) + 1;
  int b = r / (TIN_ - 1);

  float wq[F_][D_], wk[F_][D_], wv[F_][D_], bqv[D_], bkv[D_], bvv[D_];
#pragma unroll
  for (int f = 0; f < F_; ++f)
#pragma unroll
    for (int d = 0; d < D_; ++d) {
      wq[f][d] = ldc(Wq, (h * F_ + f) * D_ + d);
      wk[f][d] = ldc(Wk, (h * F_ + f) * D_ + d);
      wv[f][d] = ldc(Wv, (h * F_ + f) * D_ + d);
    }
#pragma unroll
  for (int d = 0; d < D_; ++d) {
    bqv[d] = ldc(bq, h * D_ + d);
    bkv[d] = ldc(bk, h * D_ + d);
    bvv[d] = ldc(bv, h * D_ + d);
  }
  float xt0 = ldc(x, ((b * TIN_ + t) * N_ + n) * F_ + 0);
  float xt1 = ldc(x, ((b * TIN_ + t) * N_ + n) * F_ + 1);
  float q[D_];
#pragma unroll
  for (int d = 0; d < D_; ++d) q[d] = xt0 * wq[0][d] + xt1 * wq[1][d] + bqv[d];

  float sc[TIN_];
  float mx = -1e30f;
#pragma unroll
  for (int s = 0; s < TIN_; ++s) {
    float xs0 = ldc(x, ((b * TIN_ + s) * N_ + n) * F_ + 0);
    float xs1 = ldc(x, ((b * TIN_ + s) * N_ + n) * F_ + 1);
    float dot = 0.f;
#pragma unroll
    for (int d = 0; d < D_; ++d)
      dot += q[d] * (xs0 * wk[0][d] + xs1 * wk[1][d] + bkv[d]);
    dot *= SCALE;
    sc[s] = (s <= t) ? dot : -1e30f;
    mx = fmaxf(mx, sc[s]);
  }
  float sum = 0.f;
#pragma unroll
  for (int s = 0; s < TIN_; ++s) {
    float p = __expf(sc[s] - mx);
    sc[s] = p;
    sum += p;
  }
  float inv = 1.0f / sum;
  float acc[D_];
#pragma unroll
  for (int d = 0; d < D_; ++d) acc[d] = 0.f;
#pragma unroll
  for (int s = 0; s < TIN_; ++s) {
    float xs0 = ldc(x, ((b * TIN_ + s) * N_ + n) * F_ + 0);
    float xs1 = ldc(x, ((b * TIN_ + s) * N_ + n) * F_ + 1);
#pragma unroll
    for (int d = 0; d < D_; ++d)
      acc[d] += sc[s] * (xs0 * wv[0][d] + xs1 * wv[1][d] + bvv[d]);
  }
  bf16* o = att_t + ((size_t)((b * 11 + (t - 1)) * N_ + n)) * C_ + h * D_;
#pragma unroll
  for (int d = 0; d < D_; ++d) o[d] = __float2bfloat16(acc[d] * inv);
}
__global__ void k_temporal(const int* dtf, const void* x, const void* Wq, const void* Wk,
                           const void* Wv, const void* bq, const void* bk, const void* bv,
                           bf16* att_t) {
  if (*dtf)
    temporal_body<float>((const float*)x, (const float*)Wq, (const float*)Wk, (const float*)Wv,
                         (const float*)bq, (const float*)bk, (const float*)bv, att_t);
  else
    temporal_body<bf16>((const bf16*)x, (const bf16*)Wq, (const bf16*)Wk, (const bf16*)Wv,
                        (const bf16*)bq, (const bf16*)bk, (const bf16*)bv, att_t);
}

// ---------------- Kernel B: spatial attention, rank-2 form ----------------
#define ST_TILES 8
#define ST_ROWS 100
#define ST_MS 8
#define ST_MLEN 100
template <typename TI>
__device__ __forceinline__ void spatial2_body(
    float2* xs, float (*M)[9], float (*Vw)[3][D_], float (*pt)[ST_ROWS][19],
    const TI* x, const TI* Wq, const TI* Wk, const TI* Wv,
    const TI* bq, const TI* bk, const TI* bv, bf16* att_st) {
  int tile = blockIdx.x, ty = blockIdx.y, b = blockIdx.z;
  int t = ty + 1;
  int tid = threadIdx.x;

  for (int m = tid; m < N_; m += 832)
    xs[m] = make_float2(ldc(x, ((b * TIN_ + t) * N_ + m) * F_ + 0),
                        ldc(x, ((b * TIN_ + t) * N_ + m) * F_ + 1));
  if (tid < 54) {
    int h = tid / 9, e = tid % 9, a = e / 3, bb = e % 3;
    float acc = 0.f;
    for (int d = 0; d < 8; ++d) {
      float qa = (a == 0) ? ldc(Wq, (h * 2 + 0) * 8 + d)
               : (a == 1) ? ldc(Wq, (h * 2 + 1) * 8 + d) : ldc(bq, h * 8 + d);
      float kb = (bb == 0) ? ldc(Wk, (h * 2 + 0) * 8 + d)
               : (bb == 1) ? ldc(Wk, (h * 2 + 1) * 8 + d) : ldc(bk, h * 8 + d);
      acc += qa * kb;
    }
    M[h][e] = acc * SCALE * LOG2E;
  }
  if (tid >= 64 && tid < 64 + 144) {
    int e = tid - 64;
    int h = e / 24, a = (e % 24) / 8, d = e % 8;
    Vw[h][a][d] = (a == 0) ? ldc(Wv, (h * 2 + 0) * 8 + d)
                : (a == 1) ? ldc(Wv, (h * 2 + 1) * 8 + d) : ldc(bv, h * 8 + d);
  }
  __syncthreads();
  if (tid < ST_ROWS * ST_MS) {
    int ms = tid / ST_ROWS, nl = tid % ST_ROWS;
    int n = tile * ST_ROWS + nl;
    float x0 = xs[n].x, x1 = xs[n].y;
    float A[6], Bc[6], Cc[6];
#pragma unroll
    for (int h = 0; h < 6; ++h) {
      A[h]  = M[h][0] * x0 + M[h][3] * x1 + M[h][6];
      Bc[h] = M[h][1] * x0 + M[h][4] * x1 + M[h][7];
      Cc[h] = M[h][2] * x0 + M[h][5] * x1 + M[h][8];
    }
    float Sp[6] = {0, 0, 0, 0, 0, 0}, S0[6] = {0, 0, 0, 0, 0, 0}, S1[6] = {0, 0, 0, 0, 0, 0};
    for (int m = ms * ST_MLEN; m < ms * ST_MLEN + ST_MLEN; ++m) {
      float2 xm = xs[m];
#pragma unroll
      for (int h = 0; h < 6; ++h) {
        float p = exp2_(A[h] * xm.x + Bc[h] * xm.y + Cc[h]);
        Sp[h] += p;
        S0[h] += p * xm.x;
        S1[h] += p * xm.y;
      }
    }
#pragma unroll
    for (int h = 0; h < 6; ++h) {
      pt[ms][nl][h * 3 + 0] = Sp[h];
      pt[ms][nl][h * 3 + 1] = S0[h];
      pt[ms][nl][h * 3 + 2] = S1[h];
    }
  }
  __syncthreads();
  if (tid < ST_ROWS) {
    int n = tile * ST_ROWS + tid;
    bf16* o = att_st + ((size_t)((b * 11 + ty) * N_ + n)) * C_;
#pragma unroll
    for (int h = 0; h < 6; ++h) {
      float Sp = 0.f, S0 = 0.f, S1 = 0.f;
#pragma unroll
      for (int ms = 0; ms < ST_MS; ++ms) {
        Sp += pt[ms][tid][h * 3 + 0];
        S0 += pt[ms][tid][h * 3 + 1];
        S1 += pt[ms][tid][h * 3 + 2];
      }
      float inv = 1.f / Sp;
#pragma unroll
      for (int d = 0; d < 8; ++d)
        o[h * 8 + d] = __float2bfloat16((S0 * Vw[h][0][d] + S1 * Vw[h][1][d] + Sp * Vw[h][2][d]) * inv);
    }
  }
}
__global__ __launch_bounds__(832) void k_spatial2(
    const int* dtf, const void* x, const void* Wq, const void* Wk, const void* Wv,
    const void* bq, const void* bk, const void* bv, bf16* att_st) {
  __shared__ float2 xs[N_];
  __shared__ float M[H_][9];
  __shared__ float Vw[H_][3][D_];
  __shared__ float pt[ST_MS][ST_ROWS][19];
  if (*dtf)
    spatial2_body<float>(xs, M, Vw, pt,
                         (const float*)x, (const float*)Wq, (const float*)Wk, (const float*)Wv,
                         (const float*)bq, (const float*)bk, (const float*)bv, att_st);
  else
    spatial2_body<bf16>(xs, M, Vw, pt,
                        (const bf16*)x, (const bf16*)Wq, (const bf16*)Wk, (const bf16*)Wv,
                        (const bf16*)bq, (const bf16*)bk, (const bf16*)bv, att_st);
}

// xfrag scatter-write helper: element (row R, flat col j in [0,144)) at step.
__device__ __forceinline__ void xfrag_store(bf16* xfrag, int R, int step, int j, float v) {
  int blk = R >> 4, cg = (R >> 2) & 3, r = R & 3;
  int g = j / 48, jj = j % 48, nt = jj >> 4, cl = jj & 15;
  size_t idx = ((((size_t)blk * 21 + step) * 9 + g * 3 + nt) * 64 + (cg * 16 + cl)) * 4 + r;
  xfrag[idx] = __float2bfloat16(v);
}

// ---------------- Kernel C: proj + encoder x-parts (LDS-staged bf16) ------
template <typename TI>
__device__ __forceinline__ void projx_body(
    unsigned short (*raw)[96], unsigned short (*WpS)[48][48],
    unsigned short (*WxS)[144], unsigned short (*catS)[104],
    const bf16* att_t, const bf16* att_st,
    const TI* Wpt, const TI* bpt, const TI* Wps, const TI* bps,
    const TI* xhr_wz, const TI* xhr_wr, const TI* xhr_wh,
    const TI* xhr_bz, const TI* xhr_br, const TI* xhr_bh,
    bf16* xfrag) {
  int tile = blockIdx.x, ty = blockIdx.y, b = blockIdx.z;
  int t = ty + 1;
  int tid = threadIdx.x;
  int rw = tid / 12, jl = tid % 12;

  for (int p = 0; p < 24; ++p) {   // WpS (4608)
    int e = tid + p * 192;
    int half = e / 2304, k = (e % 2304) / 48, i = e % 48;
    WpS[half][k][i] = f2u(half ? ldc(Wps, k * 48 + i) : ldc(Wpt, k * 48 + i));
  }
  for (int p = 0; p < 32; ++p) {   // raw att rows (6144)
    int e = tid + p * 192;
    int rr = e / 96, c = e % 96;
    int n = tile * 64 + rr; if (n > 799) n = 799;
    size_t base = ((size_t)((b * 11 + ty) * N_ + n)) * C_;
    bf16 v = (c < 48) ? att_t[base + c] : att_st[base + (c - 48)];
    raw[rr][c] = __bfloat16_as_ushort(v);
  }
  for (int p = 0; p < 72; ++p) {   // WxS (13824)
    int e = tid + p * 192;
    int i = e / 144, jg = e % 144, g = jg / 48, j = jg % 48;
    const TI* w = (g == 0) ? xhr_wz : (g == 1) ? xhr_wr : xhr_wh;
    WxS[i][jg] = f2u(ldc(w, ((size_t)t * 144 + i) * 48 + j));
  }
  __syncthreads();
  {  // phase 1: cat = att @ Wp + bp -> catS[.][jl*8+m]
    int half = (jl >= 6);
    int ii0 = jl * 8 - half * 48;
    float acc[4][8];
#pragma unroll
    for (int q = 0; q < 4; ++q)
#pragma unroll
      for (int m = 0; m < 8; ++m)
        acc[q][m] = half ? ldc(bps, ii0 + m) : ldc(bpt, ii0 + m);
    for (int k = 0; k < 48; ++k) {
      float rv[4];
#pragma unroll
      for (int q = 0; q < 4; ++q) rv[q] = bfu(raw[rw * 4 + q][half * 48 + k]);
      ushort4 wa = *(const ushort4*)&WpS[half][k][ii0];
      ushort4 wb = *(const ushort4*)&WpS[half][k][ii0 + 4];
      float w8[8] = {bfu(wa.x), bfu(wa.y), bfu(wa.z), bfu(wa.w),
                     bfu(wb.x), bfu(wb.y), bfu(wb.z), bfu(wb.w)};
#pragma unroll
      for (int q = 0; q < 4; ++q)
#pragma unroll
        for (int m = 0; m < 8; ++m) acc[q][m] += rv[q] * w8[m];
    }
#pragma unroll
    for (int q = 0; q < 4; ++q)
#pragma unroll
      for (int m = 0; m < 8; ++m)
        catS[rw * 4 + q][jl * 8 + m] = f2u(acc[q][m]);
  }
  __syncthreads();
  {  // phase 2: encx = cat @ WxS + bias, scatter to xfrag
    int j0r = jl * 12;
    int g = j0r / 48, jj0 = j0r % 48;
    const TI* bx = (g == 0) ? xhr_bz : (g == 1) ? xhr_br : xhr_bh;
    float acc[4][12];
#pragma unroll
    for (int q = 0; q < 4; ++q)
#pragma unroll
      for (int m = 0; m < 12; ++m) acc[q][m] = 0.f;
    for (int i = 0; i < 96; ++i) {
      ushort4 wa = *(const ushort4*)&WxS[i][j0r];
      ushort4 wb = *(const ushort4*)&WxS[i][j0r + 4];
      ushort4 wc = *(const ushort4*)&WxS[i][j0r + 8];
      float w12[12] = {bfu(wa.x), bfu(wa.y), bfu(wa.z), bfu(wa.w),
                       bfu(wb.x), bfu(wb.y), bfu(wb.z), bfu(wb.w),
                       bfu(wc.x), bfu(wc.y), bfu(wc.z), bfu(wc.w)};
      float cv[4];
#pragma unroll
      for (int q = 0; q < 4; ++q) cv[q] = bfu(catS[rw * 4 + q][i]);
#pragma unroll
      for (int q = 0; q < 4; ++q)
#pragma unroll
        for (int m = 0; m < 12; ++m) acc[q][m] += cv[q] * w12[m];
    }
#pragma unroll
    for (int q = 0; q < 4; ++q) {
      int n = tile * 64 + rw * 4 + q;
      if (n < 800) {
        int R = b * 800 + n;
#pragma unroll
        for (int m = 0; m < 12; ++m) {
          float v = acc[q][m] + ldc(bx, ((size_t)t * N_ + n) * C_ + jj0 + m);
          xfrag_store(xfrag, R, ty, j0r + m, v);
        }
      }
    }
  }
}
__global__ __launch_bounds__(192) void k_projx(
    const int* dtf, const bf16* att_t, const bf16* att_st,
    const void* Wpt, const void* bpt, const void* Wps, const void* bps,
    const void* xwz, const void* xwr, const void* xwh,
    const void* xbz, const void* xbr, const void* xbh, bf16* xfrag) {
  __shared__ unsigned short raw[64][96];       // 12.3 KB
  __shared__ unsigned short WpS[2][48][48];    // 9.2 KB
  __shared__ unsigned short WxS[96][144];      // 27.6 KB
  __shared__ unsigned short catS[64][104];     // 13.3 KB
  if (*dtf)
    projx_body<float>(raw, WpS, WxS, catS, att_t, att_st,
                      (const float*)Wpt, (const float*)bpt, (const float*)Wps,
                      (const float*)bps, (const float*)xwz, (const float*)xwr, (const float*)xwh,
                      (const float*)xbz, (const float*)xbr, (const float*)xbh, xfrag);
  else
    projx_body<bf16>(raw, WpS, WxS, catS, att_t, att_st,
                     (const bf16*)Wpt, (const bf16*)bpt, (const bf16*)Wps,
                     (const bf16*)bps, (const bf16*)xwz, (const bf16*)xwr, (const bf16*)xwh,
                     (const bf16*)xbz, (const bf16*)xbr, (const bf16*)xbh, xfrag);
}

// ---------------- Kernel D: conv1 + decoder x-parts -----------------------
template <typename TI>
__device__ __forceinline__ void convx_body(
    float (*tpw)[KW_][2], float (*cw)[KW_][48], float (*preS)[48], float (*Wlx)[144],
    const TI* x, const TI* T,
    const TI* conv1_w, const TI* conv1_b,
    const TI* lwz, const TI* lwr, const TI* lwh,
    const TI* lbz, const TI* lbr, const TI* lbh,
    bf16* xfrag) {
  int tile = blockIdx.x, t = blockIdx.y, b = blockIdx.z;
  int tid = threadIdx.x;
  int rw = tid / 12, jl = tid % 12;

  for (int p = 0; p < 7; ++p) {
    int e = tid + p * 192;
    int f = e / (KW_ * 48), rem = e % (KW_ * 48), k = rem / 48, c = rem % 48;
    cw[f][k][c] = ldc(conv1_w, (c * F_ + f) * KW_ + k);
  }
  for (int p = 0; p < 10; ++p) {
    int e = tid + p * 192;
    if (e < 64 * KW_ * 2) {
      int rr = e / (KW_ * 2), rem = e % (KW_ * 2), k = rem / 2, f = rem % 2;
      int n = tile * 64 + rr; if (n > 799) n = 799;
      int tau = t + k;
      float v;
      if (tau < TIN_) v = ldc(x, ((size_t)(b * TIN_ + tau) * N_ + n) * F_ + f);
      else if (tau < TIN_ + TP_) v = (f == 0) ? 0.f : ldc(T, (size_t)(b * TP_ + (tau - TIN_)) * N_ + n);
      else v = ldc(x, ((size_t)(b * TIN_ + 0) * N_ + n) * F_ + f);
      tpw[rr][k][f] = v;
    }
  }
  for (int p = 0; p < 36; ++p) {
    int e = tid + p * 192;
    int i = e / 144, jg = e % 144, g = jg / 48, j = jg % 48;
    const TI* w = (g == 0) ? lwz : (g == 1) ? lwr : lwh;
    Wlx[i][jg] = ldc(w, ((size_t)t * 96 + i) * 48 + j);
  }
  __syncthreads();
  {
    int c0 = jl * 4;
    float acc[4][4];
#pragma unroll
    for (int q = 0; q < 4; ++q)
#pragma unroll
      for (int m = 0; m < 4; ++m) acc[q][m] = ldc(conv1_b, c0 + m);
#pragma unroll
    for (int f = 0; f < 2; ++f)
      for (int k = 0; k < KW_; ++k) {
        const float4 w4 = *(const float4*)&cw[f][k][c0];
        float wv[4] = {w4.x, w4.y, w4.z, w4.w};
#pragma unroll
        for (int q = 0; q < 4; ++q) {
          float tv = tpw[rw * 4 + q][k][f];
#pragma unroll
          for (int m = 0; m < 4; ++m) acc[q][m] += tv * wv[m];
        }
      }
#pragma unroll
    for (int q = 0; q < 4; ++q)
      *(float4*)&preS[rw * 4 + q][c0] = make_float4(acc[q][0], acc[q][1], acc[q][2], acc[q][3]);
  }
  __syncthreads();
  {
    int j0r = jl * 12;
    int g = j0r / 48, jj0 = j0r % 48;
    const TI* bx = (g == 0) ? lbz : (g == 1) ? lbr : lbh;
    float acc[4][12];
#pragma unroll
    for (int q = 0; q < 4; ++q)
#pragma unroll
      for (int m = 0; m < 12; ++m) acc[q][m] = 0.f;
    for (int i = 0; i < 48; ++i) {
      const float4 wa = *(const float4*)&Wlx[i][j0r];
      const float4 wb = *(const float4*)&Wlx[i][j0r + 4];
      const float4 wc = *(const float4*)&Wlx[i][j0r + 8];
      float w12[12] = {wa.x, wa.y, wa.z, wa.w, wb.x, wb.y, wb.z, wb.w, wc.x, wc.y, wc.z, wc.w};
      float pv[4];
#pragma unroll
      for (int q = 0; q < 4; ++q) pv[q] = preS[rw * 4 + q][i];
#pragma unroll
      for (int q = 0; q < 4; ++q)
#pragma unroll
        for (int m = 0; m < 12; ++m) acc[q][m] += pv[q] * w12[m];
    }
#pragma unroll
    for (int q = 0; q < 4; ++q) {
      int n = tile * 64 + rw * 4 + q;
      if (n < 800) {
        int R = b * 800 + n;
#pragma unroll
        for (int m = 0; m < 12; ++m) {
          float v = acc[q][m] + ldc(bx, ((size_t)t * N_ + n) * C_ + jj0 + m);
          xfrag_store(xfrag, R, 11 + t, j0r + m, v);
        }
      }
    }
  }
}
__global__ __launch_bounds__(192) void k_convx(
    const int* dtf, const void* x, const void* T, const void* cw_, const void* cb,
    const void* lwz, const void* lwr, const void* lwh,
    const void* lbz, const void* lbr, const void* lbh, bf16* xfrag) {
  __shared__ float tpw[64][KW_][2];
  __shared__ float cw[2][KW_][48];
  __shared__ float preS[64][48];
  __shared__ float Wlx[48][144];
  if (*dtf)
    convx_body<float>(tpw, cw, preS, Wlx,
                      (const float*)x, (const float*)T, (const float*)cw_, (const float*)cb,
                      (const float*)lwz, (const float*)lwr, (const float*)lwh,
                      (const float*)lbz, (const float*)lbr, (const float*)lbh, xfrag);
  else
    convx_body<bf16>(tpw, cw, preS, Wlx,
                     (const bf16*)x, (const bf16*)T, (const bf16*)cw_, (const bf16*)cb,
                     (const bf16*)lwz, (const bf16*)lwr, (const bf16*)lwh,
                     (const bf16*)lbz, (const bf16*)lbr, (const bf16*)lbh, xfrag);
}

// ---------------- Kernel E: MFMA GRU, x-parts bulk-staged in LDS ----------
// 100 blocks x 64 thr (1 wave = 16 rows). Per step: 9 LDS b64 x-reads
// (register-pipelined), weights register-prefetched from pre-packed global.
template <typename TI, typename TO>
__device__ __forceinline__ void gru6_body(
    unsigned short* xst, unsigned short (*hT)[72], unsigned short (*rhT)[72],
    const unsigned short* xfrag, const unsigned short* pwb,
    const TI* Wout, const TI* bout, TO* out) {
  int l = threadIdx.x;          // 64
  int cg = l >> 4, cl = l & 15;
  int blk = blockIdx.x;
  int b = blk / 50;
  int n0 = (blk % 50) * 16;

  // bulk-stage this block's x-parts (contiguous) into LDS
  {
    const unsigned short* src = xfrag + (size_t)blk * 48384;
#pragma unroll 4
    for (int it = 0; it < 95; ++it) {
      int e = it * 512 + l * 8;
      if (e < 48384) *(us8*)&xst[e] = *(const us8*)&src[e];
    }
  }
  for (int e = l; e < 16 * 72; e += 64) { (&hT[0][0])[e] = 0; (&rhT[0][0])[e] = 0; }
  float wo[3], bo = ldc(bout, 0);
#pragma unroll
  for (int nt = 0; nt < 3; ++nt) wo[nt] = ldc(Wout, nt * 16 + cl);
  float ho[3][4];
#pragma unroll
  for (int nt = 0; nt < 3; ++nt)
#pragma unroll
    for (int r = 0; r < 4; ++r) ho[nt][r] = 0.f;

  s8b wz[3][2], wr[3][2], wh[3][2];
  {  // step-0 weights
    const unsigned short* pb = pwb + (size_t)l * 8;
#pragma unroll
    for (int nt = 0; nt < 3; ++nt)
#pragma unroll
      for (int c = 0; c < 2; ++c) {
        wz[nt][c] = *(const s8b*)(pb + 0 * 9216 + nt * 3072 + c * 1536);
        wr[nt][c] = *(const s8b*)(pb + 1 * 9216 + nt * 3072 + c * 1536);
        wh[nt][c] = *(const s8b*)(pb + 2 * 9216 + nt * 3072 + c * 1536);
      }
  }
  __syncthreads();  // xst + hT/rhT ready (also drains staging loads)

  ushort4 cx[9];   // current step x-fragments
#pragma unroll
  for (int gn = 0; gn < 9; ++gn)
    cx[gn] = *(const ushort4*)&xst[gn * 256 + l * 4];

  for (int step = 0; step < 21; ++step) {
    s8b hA0 = *(const s8b*)&hT[cl][cg * 8];
    s8b hA1 = *(const s8b*)&hT[cl][32 + cg * 8];
    f4 az[3], ar[3];
#pragma unroll
    for (int nt = 0; nt < 3; ++nt) {
      f4 cz = {bfu(cx[nt].x), bfu(cx[nt].y), bfu(cx[nt].z), bfu(cx[nt].w)};
      cz = __builtin_amdgcn_mfma_f32_16x16x32_bf16(hA0, wz[nt][0], cz, 0, 0, 0);
      cz = __builtin_amdgcn_mfma_f32_16x16x32_bf16(hA1, wz[nt][1], cz, 0, 0, 0);
      az[nt] = cz;
      f4 cr = {bfu(cx[3 + nt].x), bfu(cx[3 + nt].y), bfu(cx[3 + nt].z), bfu(cx[3 + nt].w)};
      cr = __builtin_amdgcn_mfma_f32_16x16x32_bf16(hA0, wr[nt][0], cr, 0, 0, 0);
      cr = __builtin_amdgcn_mfma_f32_16x16x32_bf16(hA1, wr[nt][1], cr, 0, 0, 0);
      ar[nt] = cr;
    }
    if (step < 20) {  // prefetch next wz/wr (global, L2-resident)
      const unsigned short* pb = pwb + (size_t)(step + 1) * 27648 + (size_t)l * 8;
#pragma unroll
      for (int nt = 0; nt < 3; ++nt)
#pragma unroll
        for (int c = 0; c < 2; ++c) {
          wz[nt][c] = *(const s8b*)(pb + 0 * 9216 + nt * 3072 + c * 1536);
          wr[nt][c] = *(const s8b*)(pb + 1 * 9216 + nt * 3072 + c * 1536);
        }
    }
    float xh_[3][4];
#pragma unroll
    for (int nt = 0; nt < 3; ++nt) {
      xh_[nt][0] = bfu(cx[6 + nt].x); xh_[nt][1] = bfu(cx[6 + nt].y);
      xh_[nt][2] = bfu(cx[6 + nt].z); xh_[nt][3] = bfu(cx[6 + nt].w);
    }
    ushort4 nx[9];
    if (step < 20) {  // prefetch next step's x from LDS
#pragma unroll
      for (int gn = 0; gn < 9; ++gn)
        nx[gn] = *(const ushort4*)&xst[((step + 1) * 9 + gn) * 256 + l * 4];
    }
    float z[3][4];
#pragma unroll
    for (int nt = 0; nt < 3; ++nt)
#pragma unroll
      for (int r = 0; r < 4; ++r) {
        z[nt][r] = sigm(az[nt][r]);
        float rv = sigm(ar[nt][r]) * ho[nt][r];
        rhT[cg * 4 + r][nt * 16 + cl] = f2u(rv);
      }
    asm volatile("" ::: "memory");  // rh writes before rh A-frag reads (wave DS in-order)
    s8b rA0 = *(const s8b*)&rhT[cl][cg * 8];
    s8b rA1 = *(const s8b*)&rhT[cl][32 + cg * 8];
    f4 ah[3];
#pragma unroll
    for (int nt = 0; nt < 3; ++nt) {
      f4 ch = {xh_[nt][0], xh_[nt][1], xh_[nt][2], xh_[nt][3]};
      ch = __builtin_amdgcn_mfma_f32_16x16x32_bf16(rA0, wh[nt][0], ch, 0, 0, 0);
      ch = __builtin_amdgcn_mfma_f32_16x16x32_bf16(rA1, wh[nt][1], ch, 0, 0, 0);
      ah[nt] = ch;
    }
    if (step < 20) {  // prefetch next wh
      const unsigned short* pb = pwb + (size_t)(step + 1) * 27648 + (size_t)l * 8;
#pragma unroll
      for (int nt = 0; nt < 3; ++nt)
#pragma unroll
        for (int c = 0; c < 2; ++c)
          wh[nt][c] = *(const s8b*)(pb + 2 * 9216 + nt * 3072 + c * 1536);
    }
    float pout[4] = {0.f, 0.f, 0.f, 0.f};
#pragma unroll
    for (int nt = 0; nt < 3; ++nt)
#pragma unroll
      for (int r = 0; r < 4; ++r) {
        float hn = (1.f - z[nt][r]) * ho[nt][r] + z[nt][r] * tanh_(ah[nt][r]);
        ho[nt][r] = hn;
        hT[cg * 4 + r][nt * 16 + cl] = f2u(hn);
        pout[r] += hn * wo[nt];
      }
    if (step >= 11) {
#pragma unroll
      for (int r = 0; r < 4; ++r) {
        float p = pout[r];
        p += __shfl_xor(p, 1);
        p += __shfl_xor(p, 2);
        p += __shfl_xor(p, 4);
        p += __shfl_xor(p, 8);
        if (cl == 0)
          sto(out, ((size_t)b * TP_ + (step - 11)) * N_ + n0 + cg * 4 + r, p + bo);
      }
    }
#pragma unroll
    for (int gn = 0; gn < 9; ++gn) cx[gn] = nx[gn];
    asm volatile("" ::: "memory");  // h writes before next-step reads
  }
}
__global__ __launch_bounds__(64) void k_gru6(
    const int* dtf, const bf16* xfrag, const bf16* pwb,
    const void* Wout, const void* bout, void* out) {
  __shared__ alignas(16) unsigned short xst[48384];   // 96,768 B: all 21 steps
  __shared__ alignas(16) unsigned short hT[16][72];
  __shared__ alignas(16) unsigned short rhT[16][72];
  if (*dtf)
    gru6_body<float, float>(xst, hT, rhT,
                            (const unsigned short*)xfrag, (const unsigned short*)pwb,
                            (const float*)Wout, (const float*)bout, (float*)out);
  else
    gru6_body<bf16, bf16>(xst, hT, rhT,
                          (const unsigned short*)xfrag, (const unsigned short*)pwb,
                          (const bf16*)Wout, (const bf16*)bout, (bf16*)out);
}

// ---------------------------------------------------------------------------
extern "C" void kernel_launch(void* const* d_in, const int* in_sizes, int n_in,
                              void* d_out, int out_size, void* d_ws, size_t ws_size,
                              hipStream_t stream) {
  (void)in_sizes; (void)n_in; (void)out_size; (void)ws_size;
  const void* x       = d_in[0];
  const void* T       = d_in[1];
  const void* Wq_t    = d_in[3];
  const void* Wk_t    = d_in[4];
  const void* Wv_t    = d_in[5];
  const void* Wq_st   = d_in[6];
  const void* Wk_st   = d_in[7];
  const void* Wv_st   = d_in[8];
  const void* bq_t    = d_in[9];
  const void* bk_t    = d_in[10];
  const void* bv_t    = d_in[11];
  const void* bq_st   = d_in[12];
  const void* bk_st   = d_in[13];
  const void* bv_st   = d_in[14];
  const void* conv1_w = d_in[15];
  const void* conv1_b = d_in[16];
  const void* Wproj_t = d_in[17];
  const void* bproj_t = d_in[18];
  const void* Wproj_st= d_in[19];
  const void* bproj_st= d_in[20];
  const void* xhr_wz  = d_in[21];
  const void* xhr_wr  = d_in[22];
  const void* xhr_wh  = d_in[23];
  const void* xhr_bz  = d_in[24];
  const void* xhr_br  = d_in[25];
  const void* xhr_bh  = d_in[26];
  const void* last_wz = d_in[27];
  const void* last_wr = d_in[28];
  const void* last_wh = d_in[29];
  const void* last_bz = d_in[30];
  const void* last_br = d_in[31];
  const void* last_bh = d_in[32];
  const void* Wout    = d_in[33];
  const void* bout    = d_in[34];

  // ws layout (~14.2 MB; 14.75 MB proven safe earlier)
  char* wsb = (char*)d_ws;
  int* dtf     = (int*)wsb;                              // 256 B
  bf16* att_t  = (bf16*)(wsb + 256);                     // 2*11*800*48
  bf16* att_st = att_t + (size_t)2 * 11 * 800 * 48;
  bf16* xfrag  = att_st + (size_t)2 * 11 * 800 * 48;     // 100*21*9*64*4 elems
  bf16* pwb    = xfrag + (size_t)100 * 21 * 9 * 64 * 4;  // 21*27648

  k_detect<<<1, 64, 0, stream>>>((const unsigned int*)x, dtf);
  k_pack<<<(21 * 27648 + 255) / 256, 256, 0, stream>>>(
      dtf, xhr_wz, xhr_wr, xhr_wh, last_wz, last_wr, last_wh, pwb);
  {
    int total = B_ * (TIN_ - 1) * H_ * N_;
    k_temporal<<<(total + 255) / 256, 256, 0, stream>>>(
        dtf, x, Wq_t, Wk_t, Wv_t, bq_t, bk_t, bv_t, att_t);
  }
  k_spatial2<<<dim3(ST_TILES, 11, 2), 832, 0, stream>>>(
      dtf, x, Wq_st, Wk_st, Wv_st, bq_st, bk_st, bv_st, att_st);
  k_convx<<<dim3(13, 10, 2), 192, 0, stream>>>(
      dtf, x, T, conv1_w, conv1_b, last_wz, last_wr, last_wh,
      last_bz, last_br, last_bh, xfrag);
  k_projx<<<dim3(13, 11, 2), 192, 0, stream>>>(
      dtf, att_t, att_st, Wproj_t, bproj_t, Wproj_st, bproj_st,
      xhr_wz, xhr_wr, xhr_wh, xhr_bz, xhr_br, xhr_bh, xfrag);
  k_gru6<<<100, 64, 0, stream>>>(
      dtf, xfrag, pwb, Wout, bout, d_out);
}

// Round 11
// 217.604 us; speedup vs baseline: 1.0456x; 1.0456x over previous
//
#include <hip/hip_runtime.h>
#include <hip/hip_bf16.h>

typedef __hip_bfloat16 bf16;
typedef __attribute__((ext_vector_type(8))) short s8b;   // 8 bf16 (4 VGPR)
typedef __attribute__((ext_vector_type(4))) float f4;    // MFMA C/D
typedef __attribute__((ext_vector_type(8))) unsigned short us8;

#define B_ 2
#define TIN_ 12
#define N_ 800
#define F_ 2
#define H_ 6
#define D_ 8
#define C_ 48
#define TP_ 10
#define KW_ 14
#define SCALE 0.35355339059327373f  // 1/sqrt(8)
#define LOG2E 1.4426950408889634f

__device__ __forceinline__ float sigm(float x) { return 1.0f / (1.0f + __expf(-x)); }
__device__ __forceinline__ float tanh_(float x) {
  float e = __expf(-2.0f * x);
  return 2.0f / (1.0f + e) - 1.0f;
}
__device__ __forceinline__ float exp2_(float x) { return __builtin_amdgcn_exp2f(x); }
__device__ __forceinline__ float bfu(unsigned short u) {
  return __uint_as_float((unsigned)u << 16);
}
__device__ __forceinline__ unsigned short f2u(float v) {
  return __bfloat16_as_ushort(__float2bfloat16(v));
}
__device__ __forceinline__ float ldc(const float* p, size_t i) { return p[i]; }
__device__ __forceinline__ float ldc(const bf16* p, size_t i) { return __bfloat162float(p[i]); }
__device__ __forceinline__ void sto(float* p, size_t i, float v) { p[i] = v; }
__device__ __forceinline__ void sto(bf16* p, size_t i, float v) { p[i] = __float2bfloat16(v); }

// ---------------- Kernel 0: dtype detector --------------------------------
__global__ void k_detect(const unsigned int* __restrict__ xw, int* __restrict__ flag) {
  int lane = threadIdx.x;  // 64
  unsigned int w = xw[lane];
  int e = (w >> 7) & 0xFF;  // exponent of LOW bf16 slot
  int bad = ((e >= 1 && e < 96) || (e > 150)) ? 1 : 0;
  unsigned long long m = __ballot(bad);
  if (lane == 0) *flag = (__popcll(m) >= 16) ? 1 : 0;
}

// ---------------- Kernel P: pack recurrent weights to MFMA B-fragments ----
template <typename TI>
__device__ __forceinline__ void pack_body(
    const TI* xwz, const TI* xwr, const TI* xwh,
    const TI* lwz, const TI* lwr, const TI* lwh, bf16* pwb) {
  int gid = blockIdx.x * 256 + threadIdx.x;
  const int total = 21 * 27648;
  if (gid >= total) return;
  int step = gid / 27648, r = gid % 27648;
  int g = r / 9216;  r %= 9216;
  int nt = r / 3072; r %= 3072;
  int c = r / 1536;  r %= 1536;
  int lane = r / 8, j = r % 8;
  int k = 32 * c + (lane >> 4) * 8 + j;
  int n = nt * 16 + (lane & 15);
  float v = 0.f;
  if (k < 48) {
    if (step < 11) {
      int t = step + 1;
      const TI* w = (g == 0) ? xwz : (g == 1) ? xwr : xwh;
      v = ldc(w, ((size_t)t * 144 + 96 + k) * 48 + n);
    } else {
      int t = step - 11;
      const TI* w = (g == 0) ? lwz : (g == 1) ? lwr : lwh;
      v = ldc(w, ((size_t)t * 96 + 48 + k) * 48 + n);
    }
  }
  pwb[gid] = __float2bfloat16(v);
}
__global__ void k_pack(const int* dtf, const void* xwz, const void* xwr, const void* xwh,
                       const void* lwz, const void* lwr, const void* lwh, bf16* pwb) {
  if (*dtf)
    pack_body<float>((const float*)xwz, (const float*)xwr, (const float*)xwh,
                     (const float*)lwz, (const float*)lwr, (const float*)lwh, pwb);
  else
    pack_body<bf16>((const bf16*)xwz, (const bf16*)xwr, (const bf16*)xwh,
                    (const bf16*)lwz, (const bf16*)lwr, (const bf16*)lwh, pwb);
}

// ---------------- Kernel A: temporal causal attention (t=1..11) -----------
template <typename TI>
__device__ __forceinline__ void temporal_body(
    const TI* x, const TI* Wq, const TI* Wk, const TI* Wv,
    const TI* bq, const TI* bk, const TI* bv, bf16* att_t) {
  int gid = blockIdx.x * blockDim.x + threadIdx.x;
  const int total = B_ * (TIN_ - 1) * H_ * N_;
  if (gid >= total) return;
  int n = gid % N_;
  int r = gid / N_;
  int h = r % H_;  r /= H_;
  int t = (r % (TIN_ - 1)) + 1;
  int b = r / (TIN_ - 1);

  float wq[F_][D_], wk[F_][D_], wv[F_][D_], bqv[D_], bkv[D_], bvv[D_];
#pragma unroll
  for (int f = 0; f < F_; ++f)
#pragma unroll
    for (int d = 0; d < D_; ++d) {
      wq[f][d] = ldc(Wq, (h * F_ + f) * D_ + d);
      wk[f][d] = ldc(Wk, (h * F_ + f) * D_ + d);
      wv[f][d] = ldc(Wv, (h * F_ + f) * D_ + d);
    }
#pragma unroll
  for (int d = 0; d < D_; ++d) {
    bqv[d] = ldc(bq, h * D_ + d);
    bkv[d] = ldc(bk, h * D_ + d);
    bvv[d] = ldc(bv, h * D_ + d);
  }
  float xt0 = ldc(x, ((b * TIN_ + t) * N_ + n) * F_ + 0);
  float xt1 = ldc(x, ((b * TIN_ + t) * N_ + n) * F_ + 1);
  float q[D_];
#pragma unroll
  for (int d = 0; d < D_; ++d) q[d] = xt0 * wq[0][d] + xt1 * wq[1][d] + bqv[d];

  float sc[TIN_];
  float mx = -1e30f;
#pragma unroll
  for (int s = 0; s < TIN_; ++s) {
    float xs0 = ldc(x, ((b * TIN_ + s) * N_ + n) * F_ + 0);
    float xs1 = ldc(x, ((b * TIN_ + s) * N_ + n) * F_ + 1);
    float dot = 0.f;
#pragma unroll
    for (int d = 0; d < D_; ++d)
      dot += q[d] * (xs0 * wk[0][d] + xs1 * wk[1][d] + bkv[d]);
    dot *= SCALE;
    sc[s] = (s <= t) ? dot : -1e30f;
    mx = fmaxf(mx, sc[s]);
  }
  float sum = 0.f;
#pragma unroll
  for (int s = 0; s < TIN_; ++s) {
    float p = __expf(sc[s] - mx);
    sc[s] = p;
    sum += p;
  }
  float inv = 1.0f / sum;
  float acc[D_];
#pragma unroll
  for (int d = 0; d < D_; ++d) acc[d] = 0.f;
#pragma unroll
  for (int s = 0; s < TIN_; ++s) {
    float xs0 = ldc(x, ((b * TIN_ + s) * N_ + n) * F_ + 0);
    float xs1 = ldc(x, ((b * TIN_ + s) * N_ + n) * F_ + 1);
#pragma unroll
    for (int d = 0; d < D_; ++d)
      acc[d] += sc[s] * (xs0 * wv[0][d] + xs1 * wv[1][d] + bvv[d]);
  }
  bf16* o = att_t + ((size_t)((b * 11 + (t - 1)) * N_ + n)) * C_ + h * D_;
#pragma unroll
  for (int d = 0; d < D_; ++d) o[d] = __float2bfloat16(acc[d] * inv);
}
__global__ void k_temporal(const int* dtf, const void* x, const void* Wq, const void* Wk,
                           const void* Wv, const void* bq, const void* bk, const void* bv,
                           bf16* att_t) {
  if (*dtf)
    temporal_body<float>((const float*)x, (const float*)Wq, (const float*)Wk, (const float*)Wv,
                         (const float*)bq, (const float*)bk, (const float*)bv, att_t);
  else
    temporal_body<bf16>((const bf16*)x, (const bf16*)Wq, (const bf16*)Wk, (const bf16*)Wv,
                        (const bf16*)bq, (const bf16*)bk, (const bf16*)bv, att_t);
}

// ---------------- Kernel B: spatial attention, rank-2 form ----------------
#define ST_TILES 8
#define ST_ROWS 100
#define ST_MS 8
#define ST_MLEN 100
template <typename TI>
__device__ __forceinline__ void spatial2_body(
    float2* xs, float (*M)[9], float (*Vw)[3][D_], float (*pt)[ST_ROWS][19],
    const TI* x, const TI* Wq, const TI* Wk, const TI* Wv,
    const TI* bq, const TI* bk, const TI* bv, bf16* att_st) {
  int tile = blockIdx.x, ty = blockIdx.y, b = blockIdx.z;
  int t = ty + 1;
  int tid = threadIdx.x;

  for (int m = tid; m < N_; m += 832)
    xs[m] = make_float2(ldc(x, ((b * TIN_ + t) * N_ + m) * F_ + 0),
                        ldc(x, ((b * TIN_ + t) * N_ + m) * F_ + 1));
  if (tid < 54) {
    int h = tid / 9, e = tid % 9, a = e / 3, bb = e % 3;
    float acc = 0.f;
    for (int d = 0; d < 8; ++d) {
      float qa = (a == 0) ? ldc(Wq, (h * 2 + 0) * 8 + d)
               : (a == 1) ? ldc(Wq, (h * 2 + 1) * 8 + d) : ldc(bq, h * 8 + d);
      float kb = (bb == 0) ? ldc(Wk, (h * 2 + 0) * 8 + d)
               : (bb == 1) ? ldc(Wk, (h * 2 + 1) * 8 + d) : ldc(bk, h * 8 + d);
      acc += qa * kb;
    }
    M[h][e] = acc * SCALE * LOG2E;
  }
  if (tid >= 64 && tid < 64 + 144) {
    int e = tid - 64;
    int h = e / 24, a = (e % 24) / 8, d = e % 8;
    Vw[h][a][d] = (a == 0) ? ldc(Wv, (h * 2 + 0) * 8 + d)
                : (a == 1) ? ldc(Wv, (h * 2 + 1) * 8 + d) : ldc(bv, h * 8 + d);
  }
  __syncthreads();
  if (tid < ST_ROWS * ST_MS) {
    int ms = tid / ST_ROWS, nl = tid % ST_ROWS;
    int n = tile * ST_ROWS + nl;
    float x0 = xs[n].x, x1 = xs[n].y;
    float A[6], Bc[6], Cc[6];
#pragma unroll
    for (int h = 0; h < 6; ++h) {
      A[h]  = M[h][0] * x0 + M[h][3] * x1 + M[h][6];
      Bc[h] = M[h][1] * x0 + M[h][4] * x1 + M[h][7];
      Cc[h] = M[h][2] * x0 + M[h][5] * x1 + M[h][8];
    }
    float Sp[6] = {0, 0, 0, 0, 0, 0}, S0[6] = {0, 0, 0, 0, 0, 0}, S1[6] = {0, 0, 0, 0, 0, 0};
    for (int m = ms * ST_MLEN; m < ms * ST_MLEN + ST_MLEN; ++m) {
      float2 xm = xs[m];
#pragma unroll
      for (int h = 0; h < 6; ++h) {
        float p = exp2_(A[h] * xm.x + Bc[h] * xm.y + Cc[h]);
        Sp[h] += p;
        S0[h] += p * xm.x;
        S1[h] += p * xm.y;
      }
    }
#pragma unroll
    for (int h = 0; h < 6; ++h) {
      pt[ms][nl][h * 3 + 0] = Sp[h];
      pt[ms][nl][h * 3 + 1] = S0[h];
      pt[ms][nl][h * 3 + 2] = S1[h];
    }
  }
  __syncthreads();
  if (tid < ST_ROWS) {
    int n = tile * ST_ROWS + tid;
    bf16* o = att_st + ((size_t)((b * 11 + ty) * N_ + n)) * C_;
#pragma unroll
    for (int h = 0; h < 6; ++h) {
      float Sp = 0.f, S0 = 0.f, S1 = 0.f;
#pragma unroll
      for (int ms = 0; ms < ST_MS; ++ms) {
        Sp += pt[ms][tid][h * 3 + 0];
        S0 += pt[ms][tid][h * 3 + 1];
        S1 += pt[ms][tid][h * 3 + 2];
      }
      float inv = 1.f / Sp;
#pragma unroll
      for (int d = 0; d < 8; ++d)
        o[h * 8 + d] = __float2bfloat16((S0 * Vw[h][0][d] + S1 * Vw[h][1][d] + Sp * Vw[h][2][d]) * inv);
    }
  }
}
__global__ __launch_bounds__(832) void k_spatial2(
    const int* dtf, const void* x, const void* Wq, const void* Wk, const void* Wv,
    const void* bq, const void* bk, const void* bv, bf16* att_st) {
  __shared__ float2 xs[N_];
  __shared__ float M[H_][9];
  __shared__ float Vw[H_][3][D_];
  __shared__ float pt[ST_MS][ST_ROWS][19];
  if (*dtf)
    spatial2_body<float>(xs, M, Vw, pt,
                         (const float*)x, (const float*)Wq, (const float*)Wk, (const float*)Wv,
                         (const float*)bq, (const float*)bk, (const float*)bv, att_st);
  else
    spatial2_body<bf16>(xs, M, Vw, pt,
                        (const bf16*)x, (const bf16*)Wq, (const bf16*)Wk, (const bf16*)Wv,
                        (const bf16*)bq, (const bf16*)bk, (const bf16*)bv, att_st);
}

// xfrag scatter-write helper: element (row R, flat col j in [0,144)) at step.
__device__ __forceinline__ void xfrag_store(bf16* xfrag, int R, int step, int j, float v) {
  int grp = R >> 4, cg = (R >> 2) & 3, r = R & 3;
  int g = j / 48, jj = j % 48, nt = jj >> 4, cl = jj & 15;
  size_t idx = ((((size_t)grp * 21 + step) * 9 + g * 3 + nt) * 64 + (cg * 16 + cl)) * 4 + r;
  xfrag[idx] = __float2bfloat16(v);
}

// ---------------- projx body (y < 11) -------------------------------------
template <typename TI>
__device__ __forceinline__ void projx_body(
    unsigned short (*raw)[96], unsigned short (*WpS)[48][48],
    unsigned short (*WxS)[144], unsigned short (*catS)[104],
    const bf16* att_t, const bf16* att_st,
    const TI* Wpt, const TI* bpt, const TI* Wps, const TI* bps,
    const TI* xhr_wz, const TI* xhr_wr, const TI* xhr_wh,
    const TI* xhr_bz, const TI* xhr_br, const TI* xhr_bh,
    bf16* xfrag) {
  int tile = blockIdx.x, ty = blockIdx.y, b = blockIdx.z;
  int t = ty + 1;
  int tid = threadIdx.x;
  int rw = tid / 12, jl = tid % 12;

#pragma unroll 8
  for (int p = 0; p < 24; ++p) {   // WpS (4608)
    int e = tid + p * 192;
    int half = e / 2304, k = (e % 2304) / 48, i = e % 48;
    WpS[half][k][i] = f2u(half ? ldc(Wps, k * 48 + i) : ldc(Wpt, k * 48 + i));
  }
#pragma unroll 8
  for (int p = 0; p < 32; ++p) {   // raw att rows (6144)
    int e = tid + p * 192;
    int rr = e / 96, c = e % 96;
    int n = tile * 64 + rr; if (n > 799) n = 799;
    size_t base = ((size_t)((b * 11 + ty) * N_ + n)) * C_;
    bf16 v = (c < 48) ? att_t[base + c] : att_st[base + (c - 48)];
    raw[rr][c] = __bfloat16_as_ushort(v);
  }
#pragma unroll 8
  for (int p = 0; p < 72; ++p) {   // WxS (13824)
    int e = tid + p * 192;
    int i = e / 144, jg = e % 144, g = jg / 48, j = jg % 48;
    const TI* w = (g == 0) ? xhr_wz : (g == 1) ? xhr_wr : xhr_wh;
    WxS[i][jg] = f2u(ldc(w, ((size_t)t * 144 + i) * 48 + j));
  }
  __syncthreads();
  {  // phase 1: cat = att @ Wp + bp -> catS[.][jl*8+m]
    int half = (jl >= 6);
    int ii0 = jl * 8 - half * 48;
    float acc[4][8];
#pragma unroll
    for (int q = 0; q < 4; ++q)
#pragma unroll
      for (int m = 0; m < 8; ++m)
        acc[q][m] = half ? ldc(bps, ii0 + m) : ldc(bpt, ii0 + m);
    for (int k = 0; k < 48; ++k) {
      float rv[4];
#pragma unroll
      for (int q = 0; q < 4; ++q) rv[q] = bfu(raw[rw * 4 + q][half * 48 + k]);
      ushort4 wa = *(const ushort4*)&WpS[half][k][ii0];
      ushort4 wb = *(const ushort4*)&WpS[half][k][ii0 + 4];
      float w8[8] = {bfu(wa.x), bfu(wa.y), bfu(wa.z), bfu(wa.w),
                     bfu(wb.x), bfu(wb.y), bfu(wb.z), bfu(wb.w)};
#pragma unroll
      for (int q = 0; q < 4; ++q)
#pragma unroll
        for (int m = 0; m < 8; ++m) acc[q][m] += rv[q] * w8[m];
    }
#pragma unroll
    for (int q = 0; q < 4; ++q)
#pragma unroll
      for (int m = 0; m < 8; ++m)
        catS[rw * 4 + q][jl * 8 + m] = f2u(acc[q][m]);
  }
  __syncthreads();
  {  // phase 2: encx = cat @ WxS + bias, scatter to xfrag
    int j0r = jl * 12;
    int g = j0r / 48, jj0 = j0r % 48;
    const TI* bx = (g == 0) ? xhr_bz : (g == 1) ? xhr_br : xhr_bh;
    float acc[4][12];
#pragma unroll
    for (int q = 0; q < 4; ++q)
#pragma unroll
      for (int m = 0; m < 12; ++m) acc[q][m] = 0.f;
    for (int i = 0; i < 96; ++i) {
      ushort4 wa = *(const ushort4*)&WxS[i][j0r];
      ushort4 wb = *(const ushort4*)&WxS[i][j0r + 4];
      ushort4 wc = *(const ushort4*)&WxS[i][j0r + 8];
      float w12[12] = {bfu(wa.x), bfu(wa.y), bfu(wa.z), bfu(wa.w),
                       bfu(wb.x), bfu(wb.y), bfu(wb.z), bfu(wb.w),
                       bfu(wc.x), bfu(wc.y), bfu(wc.z), bfu(wc.w)};
      float cv[4];
#pragma unroll
      for (int q = 0; q < 4; ++q) cv[q] = bfu(catS[rw * 4 + q][i]);
#pragma unroll
      for (int q = 0; q < 4; ++q)
#pragma unroll
        for (int m = 0; m < 12; ++m) acc[q][m] += cv[q] * w12[m];
    }
#pragma unroll
    for (int q = 0; q < 4; ++q) {
      int n = tile * 64 + rw * 4 + q;
      if (n < 800) {
        int R = b * 800 + n;
#pragma unroll
        for (int m = 0; m < 12; ++m) {
          float v = acc[q][m] + ldc(bx, ((size_t)t * N_ + n) * C_ + jj0 + m);
          xfrag_store(xfrag, R, ty, j0r + m, v);
        }
      }
    }
  }
}

// ---------------- convx body (y >= 11, t = y-11) ---------------------------
template <typename TI>
__device__ __forceinline__ void convx_body(
    float (*tpw)[KW_][2], float (*cw)[KW_][48], float (*preS)[48], float (*Wlx)[144],
    int t,
    const TI* x, const TI* T,
    const TI* conv1_w, const TI* conv1_b,
    const TI* lwz, const TI* lwr, const TI* lwh,
    const TI* lbz, const TI* lbr, const TI* lbh,
    bf16* xfrag) {
  int tile = blockIdx.x, b = blockIdx.z;
  int tid = threadIdx.x;
  int rw = tid / 12, jl = tid % 12;

#pragma unroll 7
  for (int p = 0; p < 7; ++p) {
    int e = tid + p * 192;
    int f = e / (KW_ * 48), rem = e % (KW_ * 48), k = rem / 48, c = rem % 48;
    cw[f][k][c] = ldc(conv1_w, (c * F_ + f) * KW_ + k);
  }
#pragma unroll 10
  for (int p = 0; p < 10; ++p) {
    int e = tid + p * 192;
    if (e < 64 * KW_ * 2) {
      int rr = e / (KW_ * 2), rem = e % (KW_ * 2), k = rem / 2, f = rem % 2;
      int n = tile * 64 + rr; if (n > 799) n = 799;
      int tau = t + k;
      float v;
      if (tau < TIN_) v = ldc(x, ((size_t)(b * TIN_ + tau) * N_ + n) * F_ + f);
      else if (tau < TIN_ + TP_) v = (f == 0) ? 0.f : ldc(T, (size_t)(b * TP_ + (tau - TIN_)) * N_ + n);
      else v = ldc(x, ((size_t)(b * TIN_ + 0) * N_ + n) * F_ + f);
      tpw[rr][k][f] = v;
    }
  }
#pragma unroll 8
  for (int p = 0; p < 36; ++p) {
    int e = tid + p * 192;
    int i = e / 144, jg = e % 144, g = jg / 48, j = jg % 48;
    const TI* w = (g == 0) ? lwz : (g == 1) ? lwr : lwh;
    Wlx[i][jg] = ldc(w, ((size_t)t * 96 + i) * 48 + j);
  }
  __syncthreads();
  {
    int c0 = jl * 4;
    float acc[4][4];
#pragma unroll
    for (int q = 0; q < 4; ++q)
#pragma unroll
      for (int m = 0; m < 4; ++m) acc[q][m] = ldc(conv1_b, c0 + m);
#pragma unroll
    for (int f = 0; f < 2; ++f)
      for (int k = 0; k < KW_; ++k) {
        const float4 w4 = *(const float4*)&cw[f][k][c0];
        float wv[4] = {w4.x, w4.y, w4.z, w4.w};
#pragma unroll
        for (int q = 0; q < 4; ++q) {
          float tv = tpw[rw * 4 + q][k][f];
#pragma unroll
          for (int m = 0; m < 4; ++m) acc[q][m] += tv * wv[m];
        }
      }
#pragma unroll
    for (int q = 0; q < 4; ++q)
      *(float4*)&preS[rw * 4 + q][c0] = make_float4(acc[q][0], acc[q][1], acc[q][2], acc[q][3]);
  }
  __syncthreads();
  {
    int j0r = jl * 12;
    int g = j0r / 48, jj0 = j0r % 48;
    const TI* bx = (g == 0) ? lbz : (g == 1) ? lbr : lbh;
    float acc[4][12];
#pragma unroll
    for (int q = 0; q < 4; ++q)
#pragma unroll
      for (int m = 0; m < 12; ++m) acc[q][m] = 0.f;
    for (int i = 0; i < 48; ++i) {
      const float4 wa = *(const float4*)&Wlx[i][j0r];
      const float4 wb = *(const float4*)&Wlx[i][j0r + 4];
      const float4 wc = *(const float4*)&Wlx[i][j0r + 8];
      float w12[12] = {wa.x, wa.y, wa.z, wa.w, wb.x, wb.y, wb.z, wb.w, wc.x, wc.y, wc.z, wc.w};
      float pv[4];
#pragma unroll
      for (int q = 0; q < 4; ++q) pv[q] = preS[rw * 4 + q][i];
#pragma unroll
      for (int q = 0; q < 4; ++q)
#pragma unroll
        for (int m = 0; m < 12; ++m) acc[q][m] += pv[q] * w12[m];
    }
#pragma unroll
    for (int q = 0; q < 4; ++q) {
      int n = tile * 64 + rw * 4 + q;
      if (n < 800) {
        int R = b * 800 + n;
#pragma unroll
        for (int m = 0; m < 12; ++m) {
          float v = acc[q][m] + ldc(bx, ((size_t)t * N_ + n) * C_ + jj0 + m);
          xfrag_store(xfrag, R, 11 + t, j0r + m, v);
        }
      }
    }
  }
}

// ---------------- Kernel CD: merged projx (y<11) + convx (y>=11) ----------
__global__ __launch_bounds__(192) void k_xparts(
    const int* dtf, const bf16* att_t, const bf16* att_st,
    const void* Wpt, const void* bpt, const void* Wps, const void* bps,
    const void* xwz, const void* xwr, const void* xwh,
    const void* xbz, const void* xbr, const void* xbh,
    const void* x, const void* T, const void* cw_, const void* cb,
    const void* lwz, const void* lwr, const void* lwh,
    const void* lbz, const void* lbr, const void* lbh, bf16* xfrag) {
  __shared__ __align__(16) char smem[62464];
  if (blockIdx.y < 11) {
    auto raw  = (unsigned short(*)[96])smem;                  // 12288 B
    auto WpS  = (unsigned short(*)[48][48])(smem + 12288);    //  9216 B
    auto WxS  = (unsigned short(*)[144])(smem + 21504);       // 27648 B
    auto catS = (unsigned short(*)[104])(smem + 49152);       // 13312 B
    if (*dtf)
      projx_body<float>(raw, WpS, WxS, catS, att_t, att_st,
                        (const float*)Wpt, (const float*)bpt, (const float*)Wps,
                        (const float*)bps, (const float*)xwz, (const float*)xwr,
                        (const float*)xwh, (const float*)xbz, (const float*)xbr,
                        (const float*)xbh, xfrag);
    else
      projx_body<bf16>(raw, WpS, WxS, catS, att_t, att_st,
                       (const bf16*)Wpt, (const bf16*)bpt, (const bf16*)Wps,
                       (const bf16*)bps, (const bf16*)xwz, (const bf16*)xwr,
                       (const bf16*)xwh, (const bf16*)xbz, (const bf16*)xbr,
                       (const bf16*)xbh, xfrag);
  } else {
    int t = blockIdx.y - 11;
    auto tpw  = (float(*)[KW_][2])smem;                       //  7168 B
    auto cw   = (float(*)[KW_][48])(smem + 7168);             //  5376 B
    auto preS = (float(*)[48])(smem + 12544);                 // 12288 B
    auto Wlx  = (float(*)[144])(smem + 24832);                // 27648 B
    if (*dtf)
      convx_body<float>(tpw, cw, preS, Wlx, t,
                        (const float*)x, (const float*)T, (const float*)cw_, (const float*)cb,
                        (const float*)lwz, (const float*)lwr, (const float*)lwh,
                        (const float*)lbz, (const float*)lbr, (const float*)lbh, xfrag);
    else
      convx_body<bf16>(tpw, cw, preS, Wlx, t,
                       (const bf16*)x, (const bf16*)T, (const bf16*)cw_, (const bf16*)cb,
                       (const bf16*)lwz, (const bf16*)lwr, (const bf16*)lwh,
                       (const bf16*)lbz, (const bf16*)lbr, (const bf16*)lbh, xfrag);
  }
}

// ---------------- Kernel E: MFMA GRU, 12 waves/block (3/SIMD) -------------
// 9 blocks x 768 thr; wave = one 16-row group (groups 0..99; >=100 idle).
// Per wave: private hT/rhT LDS slice, zero barriers; x + weights prefetched
// from global one step ahead. 3 waves/SIMD hide L2/LDS latency.
template <typename TI, typename TO>
__device__ __forceinline__ void gru7_body(
    unsigned short* hTa, unsigned short* rhTa,
    const unsigned short* xfrag, const unsigned short* pwb,
    const TI* Wout, const TI* bout, TO* out) {
  int tid = threadIdx.x;
  int wv = tid >> 6, l = tid & 63;
  int grp = blockIdx.x * 12 + wv;
  if (grp >= 100) return;
  int cg = l >> 4, cl = l & 15;
  int b = grp / 50, n0 = (grp % 50) * 16;
  unsigned short* hT = hTa + wv * 1152;    // [16][72] pitch 72
  unsigned short* rhT = rhTa + wv * 1152;

  for (int e = l; e < 1152; e += 64) { hT[e] = 0; rhT[e] = 0; }
  float wo[3], bo = ldc(bout, 0);
#pragma unroll
  for (int nt = 0; nt < 3; ++nt) wo[nt] = ldc(Wout, nt * 16 + cl);
  float ho[3][4];
#pragma unroll
  for (int nt = 0; nt < 3; ++nt)
#pragma unroll
    for (int r = 0; r < 4; ++r) ho[nt][r] = 0.f;

  const unsigned short* xg = xfrag + (size_t)grp * 21 * 2304;
  s8b wz[3][2], wr[3][2], wh[3][2];
  ushort4 cx[9];
  {  // step-0 weights + x
    const unsigned short* pb = pwb + (size_t)l * 8;
#pragma unroll
    for (int nt = 0; nt < 3; ++nt)
#pragma unroll
      for (int c = 0; c < 2; ++c) {
        wz[nt][c] = *(const s8b*)(pb + 0 * 9216 + nt * 3072 + c * 1536);
        wr[nt][c] = *(const s8b*)(pb + 1 * 9216 + nt * 3072 + c * 1536);
        wh[nt][c] = *(const s8b*)(pb + 2 * 9216 + nt * 3072 + c * 1536);
      }
#pragma unroll
    for (int gn = 0; gn < 9; ++gn)
      cx[gn] = *(const ushort4*)(xg + gn * 256 + l * 4);
  }
  asm volatile("" ::: "memory");  // hT zero-fill ordered before A-frag reads

  for (int step = 0; step < 21; ++step) {
    s8b hA0 = *(const s8b*)&hT[cl * 72 + cg * 8];
    s8b hA1 = *(const s8b*)&hT[cl * 72 + 32 + cg * 8];
    f4 az[3], ar[3];
#pragma unroll
    for (int nt = 0; nt < 3; ++nt) {
      f4 cz = {bfu(cx[nt].x), bfu(cx[nt].y), bfu(cx[nt].z), bfu(cx[nt].w)};
      cz = __builtin_amdgcn_mfma_f32_16x16x32_bf16(hA0, wz[nt][0], cz, 0, 0, 0);
      cz = __builtin_amdgcn_mfma_f32_16x16x32_bf16(hA1, wz[nt][1], cz, 0, 0, 0);
      az[nt] = cz;
      f4 cr = {bfu(cx[3 + nt].x), bfu(cx[3 + nt].y), bfu(cx[3 + nt].z), bfu(cx[3 + nt].w)};
      cr = __builtin_amdgcn_mfma_f32_16x16x32_bf16(hA0, wr[nt][0], cr, 0, 0, 0);
      cr = __builtin_amdgcn_mfma_f32_16x16x32_bf16(hA1, wr[nt][1], cr, 0, 0, 0);
      ar[nt] = cr;
    }
    if (step < 20) {  // prefetch next wz/wr (L2-resident, shared by all waves)
      const unsigned short* pb = pwb + (size_t)(step + 1) * 27648 + (size_t)l * 8;
#pragma unroll
      for (int nt = 0; nt < 3; ++nt)
#pragma unroll
        for (int c = 0; c < 2; ++c) {
          wz[nt][c] = *(const s8b*)(pb + 0 * 9216 + nt * 3072 + c * 1536);
          wr[nt][c] = *(const s8b*)(pb + 1 * 9216 + nt * 3072 + c * 1536);
        }
    }
    float xh_[3][4];
#pragma unroll
    for (int nt = 0; nt < 3; ++nt) {
      xh_[nt][0] = bfu(cx[6 + nt].x); xh_[nt][1] = bfu(cx[6 + nt].y);
      xh_[nt][2] = bfu(cx[6 + nt].z); xh_[nt][3] = bfu(cx[6 + nt].w);
    }
    ushort4 nx[9];
    if (step < 20) {  // prefetch next step's x (global)
#pragma unroll
      for (int gn = 0; gn < 9; ++gn)
        nx[gn] = *(const ushort4*)(xg + (step + 1) * 2304 + gn * 256 + l * 4);
    }
    float z[3][4];
#pragma unroll
    for (int nt = 0; nt < 3; ++nt)
#pragma unroll
      for (int r = 0; r < 4; ++r) {
        z[nt][r] = sigm(az[nt][r]);
        float rv = sigm(ar[nt][r]) * ho[nt][r];
        rhT[(cg * 4 + r) * 72 + nt * 16 + cl] = f2u(rv);
      }
    asm volatile("" ::: "memory");  // rh writes before rh A-frag reads (wave DS in-order)
    s8b rA0 = *(const s8b*)&rhT[cl * 72 + cg * 8];
    s8b rA1 = *(const s8b*)&rhT[cl * 72 + 32 + cg * 8];
    f4 ah[3];
#pragma unroll
    for (int nt = 0; nt < 3; ++nt) {
      f4 ch = {xh_[nt][0], xh_[nt][1], xh_[nt][2], xh_[nt][3]};
      ch = __builtin_amdgcn_mfma_f32_16x16x32_bf16(rA0, wh[nt][0], ch, 0, 0, 0);
      ch = __builtin_amdgcn_mfma_f32_16x16x32_bf16(rA1, wh[nt][1], ch, 0, 0, 0);
      ah[nt] = ch;
    }
    if (step < 20) {  // prefetch next wh
      const unsigned short* pb = pwb + (size_t)(step + 1) * 27648 + (size_t)l * 8;
#pragma unroll
      for (int nt = 0; nt < 3; ++nt)
#pragma unroll
        for (int c = 0; c < 2; ++c)
          wh[nt][c] = *(const s8b*)(pb + 2 * 9216 + nt * 3072 + c * 1536);
    }
    float pout[4] = {0.f, 0.f, 0.f, 0.f};
#pragma unroll
    for (int nt = 0; nt < 3; ++nt)
#pragma unroll
      for (int r = 0; r < 4; ++r) {
        float hn = (1.f - z[nt][r]) * ho[nt][r] + z[nt][r] * tanh_(ah[nt][r]);
        ho[nt][r] = hn;
        hT[(cg * 4 + r) * 72 + nt * 16 + cl] = f2u(hn);
        pout[r] += hn * wo[nt];
      }
    if (step >= 11) {
#pragma unroll
      for (int r = 0; r < 4; ++r) {
        float p = pout[r];
        p += __shfl_xor(p, 1);
        p += __shfl_xor(p, 2);
        p += __shfl_xor(p, 4);
        p += __shfl_xor(p, 8);
        if (cl == 0)
          sto(out, ((size_t)b * TP_ + (step - 11)) * N_ + n0 + cg * 4 + r, p + bo);
      }
    }
#pragma unroll
    for (int gn = 0; gn < 9; ++gn) cx[gn] = nx[gn];
    asm volatile("" ::: "memory");  // h writes before next-step reads
  }
}
__global__ __launch_bounds__(768) void k_gru7(
    const int* dtf, const bf16* xfrag, const bf16* pwb,
    const void* Wout, const void* bout, void* out) {
  __shared__ alignas(16) unsigned short hTa[12 * 1152];
  __shared__ alignas(16) unsigned short rhTa[12 * 1152];
  if (*dtf)
    gru7_body<float, float>(hTa, rhTa,
                            (const unsigned short*)xfrag, (const unsigned short*)pwb,
                            (const float*)Wout, (const float*)bout, (float*)out);
  else
    gru7_body<bf16, bf16>(hTa, rhTa,
                          (const unsigned short*)xfrag, (const unsigned short*)pwb,
                          (const bf16*)Wout, (const bf16*)bout, (bf16*)out);
}

// ---------------------------------------------------------------------------
extern "C" void kernel_launch(void* const* d_in, const int* in_sizes, int n_in,
                              void* d_out, int out_size, void* d_ws, size_t ws_size,
                              hipStream_t stream) {
  (void)in_sizes; (void)n_in; (void)out_size; (void)ws_size;
  const void* x       = d_in[0];
  const void* T       = d_in[1];
  const void* Wq_t    = d_in[3];
  const void* Wk_t    = d_in[4];
  const void* Wv_t    = d_in[5];
  const void* Wq_st   = d_in[6];
  const void* Wk_st   = d_in[7];
  const void* Wv_st   = d_in[8];
  const void* bq_t    = d_in[9];
  const void* bk_t    = d_in[10];
  const void* bv_t    = d_in[11];
  const void* bq_st   = d_in[12];
  const void* bk_st   = d_in[13];
  const void* bv_st   = d_in[14];
  const void* conv1_w = d_in[15];
  const void* conv1_b = d_in[16];
  const void* Wproj_t = d_in[17];
  const void* bproj_t = d_in[18];
  const void* Wproj_st= d_in[19];
  const void* bproj_st= d_in[20];
  const void* xhr_wz  = d_in[21];
  const void* xhr_wr  = d_in[22];
  const void* xhr_wh  = d_in[23];
  const void* xhr_bz  = d_in[24];
  const void* xhr_br  = d_in[25];
  const void* xhr_bh  = d_in[26];
  const void* last_wz = d_in[27];
  const void* last_wr = d_in[28];
  const void* last_wh = d_in[29];
  const void* last_bz = d_in[30];
  const void* last_br = d_in[31];
  const void* last_bh = d_in[32];
  const void* Wout    = d_in[33];
  const void* bout    = d_in[34];

  // ws layout (~14.2 MB; 14.75 MB proven safe earlier)
  char* wsb = (char*)d_ws;
  int* dtf     = (int*)wsb;                              // 256 B
  bf16* att_t  = (bf16*)(wsb + 256);                     // 2*11*800*48
  bf16* att_st = att_t + (size_t)2 * 11 * 800 * 48;
  bf16* xfrag  = att_st + (size_t)2 * 11 * 800 * 48;     // 100*21*9*64*4 elems
  bf16* pwb    = xfrag + (size_t)100 * 21 * 9 * 64 * 4;  // 21*27648

  k_detect<<<1, 64, 0, stream>>>((const unsigned int*)x, dtf);
  k_pack<<<(21 * 27648 + 255) / 256, 256, 0, stream>>>(
      dtf, xhr_wz, xhr_wr, xhr_wh, last_wz, last_wr, last_wh, pwb);
  {
    int total = B_ * (TIN_ - 1) * H_ * N_;
    k_temporal<<<(total + 255) / 256, 256, 0, stream>>>(
        dtf, x, Wq_t, Wk_t, Wv_t, bq_t, bk_t, bv_t, att_t);
  }
  k_spatial2<<<dim3(ST_TILES, 11, 2), 832, 0, stream>>>(
      dtf, x, Wq_st, Wk_st, Wv_st, bq_st, bk_st, bv_st, att_st);
  k_xparts<<<dim3(13, 21, 2), 192, 0, stream>>>(
      dtf, att_t, att_st, Wproj_t, bproj_t, Wproj_st, bproj_st,
      xhr_wz, xhr_wr, xhr_wh, xhr_bz, xhr_br, xhr_bh,
      x, T, conv1_w, conv1_b, last_wz, last_wr, last_wh,
      last_bz, last_br, last_bh, xfrag);
  k_gru7<<<9, 768, 0, stream>>>(
      dtf, xfrag, pwb, Wout, bout, d_out);
}

// Round 12
// 168.539 us; speedup vs baseline: 1.3499x; 1.2911x over previous
//
#include <hip/hip_runtime.h>
#include <hip/hip_bf16.h>

typedef __hip_bfloat16 bf16;
typedef __attribute__((ext_vector_type(8))) short s8b;   // 8 bf16 (4 VGPR)
typedef __attribute__((ext_vector_type(4))) float f4;    // MFMA C/D
typedef __attribute__((ext_vector_type(8))) unsigned short us8;

#define B_ 2
#define TIN_ 12
#define N_ 800
#define F_ 2
#define H_ 6
#define D_ 8
#define C_ 48
#define TP_ 10
#define KW_ 14
#define SCALE 0.35355339059327373f  // 1/sqrt(8)
#define LOG2E 1.4426950408889634f

__device__ __forceinline__ float sigm(float x) { return 1.0f / (1.0f + __expf(-x)); }
__device__ __forceinline__ float tanh_(float x) {
  float e = __expf(-2.0f * x);
  return 2.0f / (1.0f + e) - 1.0f;
}
__device__ __forceinline__ float exp2_(float x) { return __builtin_amdgcn_exp2f(x); }
__device__ __forceinline__ float bfu(unsigned short u) {
  return __uint_as_float((unsigned)u << 16);
}
__device__ __forceinline__ unsigned short f2u(float v) {
  return __bfloat16_as_ushort(__float2bfloat16(v));
}
__device__ __forceinline__ float ldc(const float* p, size_t i) { return p[i]; }
__device__ __forceinline__ float ldc(const bf16* p, size_t i) { return __bfloat162float(p[i]); }
__device__ __forceinline__ void sto(float* p, size_t i, float v) { p[i] = v; }
__device__ __forceinline__ void sto(bf16* p, size_t i, float v) { p[i] = __float2bfloat16(v); }

// ---------------- Kernel 0: dtype detector --------------------------------
__global__ void k_detect(const unsigned int* __restrict__ xw, int* __restrict__ flag) {
  int lane = threadIdx.x;  // 64
  unsigned int w = xw[lane];
  int e = (w >> 7) & 0xFF;  // exponent of LOW bf16 slot
  int bad = ((e >= 1 && e < 96) || (e > 150)) ? 1 : 0;
  unsigned long long m = __ballot(bad);
  if (lane == 0) *flag = (__popcll(m) >= 16) ? 1 : 0;
}

// ---------------- Kernel P: pack recurrent weights to MFMA B-fragments ----
template <typename TI>
__device__ __forceinline__ void pack_body(
    const TI* xwz, const TI* xwr, const TI* xwh,
    const TI* lwz, const TI* lwr, const TI* lwh, bf16* pwb) {
  int gid = blockIdx.x * 256 + threadIdx.x;
  const int total = 21 * 27648;
  if (gid >= total) return;
  int step = gid / 27648, r = gid % 27648;
  int g = r / 9216;  r %= 9216;
  int nt = r / 3072; r %= 3072;
  int c = r / 1536;  r %= 1536;
  int lane = r / 8, j = r % 8;
  int k = 32 * c + (lane >> 4) * 8 + j;
  int n = nt * 16 + (lane & 15);
  float v = 0.f;
  if (k < 48) {
    if (step < 11) {
      int t = step + 1;
      const TI* w = (g == 0) ? xwz : (g == 1) ? xwr : xwh;
      v = ldc(w, ((size_t)t * 144 + 96 + k) * 48 + n);
    } else {
      int t = step - 11;
      const TI* w = (g == 0) ? lwz : (g == 1) ? lwr : lwh;
      v = ldc(w, ((size_t)t * 96 + 48 + k) * 48 + n);
    }
  }
  pwb[gid] = __float2bfloat16(v);
}
__global__ void k_pack(const int* dtf, const void* xwz, const void* xwr, const void* xwh,
                       const void* lwz, const void* lwr, const void* lwh, bf16* pwb) {
  if (*dtf)
    pack_body<float>((const float*)xwz, (const float*)xwr, (const float*)xwh,
                     (const float*)lwz, (const float*)lwr, (const float*)lwh, pwb);
  else
    pack_body<bf16>((const bf16*)xwz, (const bf16*)xwr, (const bf16*)xwh,
                    (const bf16*)lwz, (const bf16*)lwr, (const bf16*)lwh, pwb);
}

// ---------------- Kernel A: temporal causal attention (t=1..11) -----------
template <typename TI>
__device__ __forceinline__ void temporal_body(
    const TI* x, const TI* Wq, const TI* Wk, const TI* Wv,
    const TI* bq, const TI* bk, const TI* bv, bf16* att_t) {
  int gid = blockIdx.x * blockDim.x + threadIdx.x;
  const int total = B_ * (TIN_ - 1) * H_ * N_;
  if (gid >= total) return;
  int n = gid % N_;
  int r = gid / N_;
  int h = r % H_;  r /= H_;
  int t = (r % (TIN_ - 1)) + 1;
  int b = r / (TIN_ - 1);

  float wq[F_][D_], wk[F_][D_], wv[F_][D_], bqv[D_], bkv[D_], bvv[D_];
#pragma unroll
  for (int f = 0; f < F_; ++f)
#pragma unroll
    for (int d = 0; d < D_; ++d) {
      wq[f][d] = ldc(Wq, (h * F_ + f) * D_ + d);
      wk[f][d] = ldc(Wk, (h * F_ + f) * D_ + d);
      wv[f][d] = ldc(Wv, (h * F_ + f) * D_ + d);
    }
#pragma unroll
  for (int d = 0; d < D_; ++d) {
    bqv[d] = ldc(bq, h * D_ + d);
    bkv[d] = ldc(bk, h * D_ + d);
    bvv[d] = ldc(bv, h * D_ + d);
  }
  float xt0 = ldc(x, ((b * TIN_ + t) * N_ + n) * F_ + 0);
  float xt1 = ldc(x, ((b * TIN_ + t) * N_ + n) * F_ + 1);
  float q[D_];
#pragma unroll
  for (int d = 0; d < D_; ++d) q[d] = xt0 * wq[0][d] + xt1 * wq[1][d] + bqv[d];

  float sc[TIN_];
  float mx = -1e30f;
#pragma unroll
  for (int s = 0; s < TIN_; ++s) {
    float xs0 = ldc(x, ((b * TIN_ + s) * N_ + n) * F_ + 0);
    float xs1 = ldc(x, ((b * TIN_ + s) * N_ + n) * F_ + 1);
    float dot = 0.f;
#pragma unroll
    for (int d = 0; d < D_; ++d)
      dot += q[d] * (xs0 * wk[0][d] + xs1 * wk[1][d] + bkv[d]);
    dot *= SCALE;
    sc[s] = (s <= t) ? dot : -1e30f;
    mx = fmaxf(mx, sc[s]);
  }
  float sum = 0.f;
#pragma unroll
  for (int s = 0; s < TIN_; ++s) {
    float p = __expf(sc[s] - mx);
    sc[s] = p;
    sum += p;
  }
  float inv = 1.0f / sum;
  float acc[D_];
#pragma unroll
  for (int d = 0; d < D_; ++d) acc[d] = 0.f;
#pragma unroll
  for (int s = 0; s < TIN_; ++s) {
    float xs0 = ldc(x, ((b * TIN_ + s) * N_ + n) * F_ + 0);
    float xs1 = ldc(x, ((b * TIN_ + s) * N_ + n) * F_ + 1);
#pragma unroll
    for (int d = 0; d < D_; ++d)
      acc[d] += sc[s] * (xs0 * wv[0][d] + xs1 * wv[1][d] + bvv[d]);
  }
  bf16* o = att_t + ((size_t)((b * 11 + (t - 1)) * N_ + n)) * C_ + h * D_;
#pragma unroll
  for (int d = 0; d < D_; ++d) o[d] = __float2bfloat16(acc[d] * inv);
}
__global__ void k_temporal(const int* dtf, const void* x, const void* Wq, const void* Wk,
                           const void* Wv, const void* bq, const void* bk, const void* bv,
                           bf16* att_t) {
  if (*dtf)
    temporal_body<float>((const float*)x, (const float*)Wq, (const float*)Wk, (const float*)Wv,
                         (const float*)bq, (const float*)bk, (const float*)bv, att_t);
  else
    temporal_body<bf16>((const bf16*)x, (const bf16*)Wq, (const bf16*)Wk, (const bf16*)Wv,
                        (const bf16*)bq, (const bf16*)bk, (const bf16*)bv, att_t);
}

// ---------------- Kernel B: spatial attention, rank-2 form ----------------
#define ST_TILES 8
#define ST_ROWS 100
#define ST_MS 8
#define ST_MLEN 100
template <typename TI>
__device__ __forceinline__ void spatial2_body(
    float2* xs, float (*M)[9], float (*Vw)[3][D_], float (*pt)[ST_ROWS][19],
    const TI* x, const TI* Wq, const TI* Wk, const TI* Wv,
    const TI* bq, const TI* bk, const TI* bv, bf16* att_st) {
  int tile = blockIdx.x, ty = blockIdx.y, b = blockIdx.z;
  int t = ty + 1;
  int tid = threadIdx.x;

  for (int m = tid; m < N_; m += 832)
    xs[m] = make_float2(ldc(x, ((b * TIN_ + t) * N_ + m) * F_ + 0),
                        ldc(x, ((b * TIN_ + t) * N_ + m) * F_ + 1));
  if (tid < 54) {
    int h = tid / 9, e = tid % 9, a = e / 3, bb = e % 3;
    float acc = 0.f;
    for (int d = 0; d < 8; ++d) {
      float qa = (a == 0) ? ldc(Wq, (h * 2 + 0) * 8 + d)
               : (a == 1) ? ldc(Wq, (h * 2 + 1) * 8 + d) : ldc(bq, h * 8 + d);
      float kb = (bb == 0) ? ldc(Wk, (h * 2 + 0) * 8 + d)
               : (bb == 1) ? ldc(Wk, (h * 2 + 1) * 8 + d) : ldc(bk, h * 8 + d);
      acc += qa * kb;
    }
    M[h][e] = acc * SCALE * LOG2E;
  }
  if (tid >= 64 && tid < 64 + 144) {
    int e = tid - 64;
    int h = e / 24, a = (e % 24) / 8, d = e % 8;
    Vw[h][a][d] = (a == 0) ? ldc(Wv, (h * 2 + 0) * 8 + d)
                : (a == 1) ? ldc(Wv, (h * 2 + 1) * 8 + d) : ldc(bv, h * 8 + d);
  }
  __syncthreads();
  if (tid < ST_ROWS * ST_MS) {
    int ms = tid / ST_ROWS, nl = tid % ST_ROWS;
    int n = tile * ST_ROWS + nl;
    float x0 = xs[n].x, x1 = xs[n].y;
    float A[6], Bc[6], Cc[6];
#pragma unroll
    for (int h = 0; h < 6; ++h) {
      A[h]  = M[h][0] * x0 + M[h][3] * x1 + M[h][6];
      Bc[h] = M[h][1] * x0 + M[h][4] * x1 + M[h][7];
      Cc[h] = M[h][2] * x0 + M[h][5] * x1 + M[h][8];
    }
    float Sp[6] = {0, 0, 0, 0, 0, 0}, S0[6] = {0, 0, 0, 0, 0, 0}, S1[6] = {0, 0, 0, 0, 0, 0};
    for (int m = ms * ST_MLEN; m < ms * ST_MLEN + ST_MLEN; ++m) {
      float2 xm = xs[m];
#pragma unroll
      for (int h = 0; h < 6; ++h) {
        float p = exp2_(A[h] * xm.x + Bc[h] * xm.y + Cc[h]);
        Sp[h] += p;
        S0[h] += p * xm.x;
        S1[h] += p * xm.y;
      }
    }
#pragma unroll
    for (int h = 0; h < 6; ++h) {
      pt[ms][nl][h * 3 + 0] = Sp[h];
      pt[ms][nl][h * 3 + 1] = S0[h];
      pt[ms][nl][h * 3 + 2] = S1[h];
    }
  }
  __syncthreads();
  if (tid < ST_ROWS) {
    int n = tile * ST_ROWS + tid;
    bf16* o = att_st + ((size_t)((b * 11 + ty) * N_ + n)) * C_;
#pragma unroll
    for (int h = 0; h < 6; ++h) {
      float Sp = 0.f, S0 = 0.f, S1 = 0.f;
#pragma unroll
      for (int ms = 0; ms < ST_MS; ++ms) {
        Sp += pt[ms][tid][h * 3 + 0];
        S0 += pt[ms][tid][h * 3 + 1];
        S1 += pt[ms][tid][h * 3 + 2];
      }
      float inv = 1.f / Sp;
#pragma unroll
      for (int d = 0; d < 8; ++d)
        o[h * 8 + d] = __float2bfloat16((S0 * Vw[h][0][d] + S1 * Vw[h][1][d] + Sp * Vw[h][2][d]) * inv);
    }
  }
}
__global__ __launch_bounds__(832) void k_spatial2(
    const int* dtf, const void* x, const void* Wq, const void* Wk, const void* Wv,
    const void* bq, const void* bk, const void* bv, bf16* att_st) {
  __shared__ float2 xs[N_];
  __shared__ float M[H_][9];
  __shared__ float Vw[H_][3][D_];
  __shared__ float pt[ST_MS][ST_ROWS][19];
  if (*dtf)
    spatial2_body<float>(xs, M, Vw, pt,
                         (const float*)x, (const float*)Wq, (const float*)Wk, (const float*)Wv,
                         (const float*)bq, (const float*)bk, (const float*)bv, att_st);
  else
    spatial2_body<bf16>(xs, M, Vw, pt,
                        (const bf16*)x, (const bf16*)Wq, (const bf16*)Wk, (const bf16*)Wv,
                        (const bf16*)bq, (const bf16*)bk, (const bf16*)bv, att_st);
}

// xfrag scatter-write helper: element (row R, flat col j in [0,144)) at step.
__device__ __forceinline__ void xfrag_store(bf16* xfrag, int R, int step, int j, float v) {
  int grp = R >> 4, cg = (R >> 2) & 3, r = R & 3;
  int g = j / 48, jj = j % 48, nt = jj >> 4, cl = jj & 15;
  size_t idx = ((((size_t)grp * 21 + step) * 9 + g * 3 + nt) * 64 + (cg * 16 + cl)) * 4 + r;
  xfrag[idx] = __float2bfloat16(v);
}

// ---------------- projx body (y < 11) -------------------------------------
template <typename TI>
__device__ __forceinline__ void projx_body(
    unsigned short (*raw)[96], unsigned short (*WpS)[48][48],
    unsigned short (*WxS)[144], unsigned short (*catS)[104],
    const bf16* att_t, const bf16* att_st,
    const TI* Wpt, const TI* bpt, const TI* Wps, const TI* bps,
    const TI* xhr_wz, const TI* xhr_wr, const TI* xhr_wh,
    const TI* xhr_bz, const TI* xhr_br, const TI* xhr_bh,
    bf16* xfrag) {
  int tile = blockIdx.x, ty = blockIdx.y, b = blockIdx.z;
  int t = ty + 1;
  int tid = threadIdx.x;
  int rw = tid / 12, jl = tid % 12;

#pragma unroll 8
  for (int p = 0; p < 24; ++p) {   // WpS (4608)
    int e = tid + p * 192;
    int half = e / 2304, k = (e % 2304) / 48, i = e % 48;
    WpS[half][k][i] = f2u(half ? ldc(Wps, k * 48 + i) : ldc(Wpt, k * 48 + i));
  }
#pragma unroll 8
  for (int p = 0; p < 32; ++p) {   // raw att rows (6144)
    int e = tid + p * 192;
    int rr = e / 96, c = e % 96;
    int n = tile * 64 + rr; if (n > 799) n = 799;
    size_t base = ((size_t)((b * 11 + ty) * N_ + n)) * C_;
    bf16 v = (c < 48) ? att_t[base + c] : att_st[base + (c - 48)];
    raw[rr][c] = __bfloat16_as_ushort(v);
  }
#pragma unroll 8
  for (int p = 0; p < 72; ++p) {   // WxS (13824)
    int e = tid + p * 192;
    int i = e / 144, jg = e % 144, g = jg / 48, j = jg % 48;
    const TI* w = (g == 0) ? xhr_wz : (g == 1) ? xhr_wr : xhr_wh;
    WxS[i][jg] = f2u(ldc(w, ((size_t)t * 144 + i) * 48 + j));
  }
  __syncthreads();
  {  // phase 1: cat = att @ Wp + bp -> catS[.][jl*8+m]
    int half = (jl >= 6);
    int ii0 = jl * 8 - half * 48;
    float acc[4][8];
#pragma unroll
    for (int q = 0; q < 4; ++q)
#pragma unroll
      for (int m = 0; m < 8; ++m)
        acc[q][m] = half ? ldc(bps, ii0 + m) : ldc(bpt, ii0 + m);
    for (int k = 0; k < 48; ++k) {
      float rv[4];
#pragma unroll
      for (int q = 0; q < 4; ++q) rv[q] = bfu(raw[rw * 4 + q][half * 48 + k]);
      ushort4 wa = *(const ushort4*)&WpS[half][k][ii0];
      ushort4 wb = *(const ushort4*)&WpS[half][k][ii0 + 4];
      float w8[8] = {bfu(wa.x), bfu(wa.y), bfu(wa.z), bfu(wa.w),
                     bfu(wb.x), bfu(wb.y), bfu(wb.z), bfu(wb.w)};
#pragma unroll
      for (int q = 0; q < 4; ++q)
#pragma unroll
        for (int m = 0; m < 8; ++m) acc[q][m] += rv[q] * w8[m];
    }
#pragma unroll
    for (int q = 0; q < 4; ++q)
#pragma unroll
      for (int m = 0; m < 8; ++m)
        catS[rw * 4 + q][jl * 8 + m] = f2u(acc[q][m]);
  }
  __syncthreads();
  {  // phase 2: encx = cat @ WxS + bias, scatter to xfrag
    int j0r = jl * 12;
    int g = j0r / 48, jj0 = j0r % 48;
    const TI* bx = (g == 0) ? xhr_bz : (g == 1) ? xhr_br : xhr_bh;
    float acc[4][12];
#pragma unroll
    for (int q = 0; q < 4; ++q)
#pragma unroll
      for (int m = 0; m < 12; ++m) acc[q][m] = 0.f;
    for (int i = 0; i < 96; ++i) {
      ushort4 wa = *(const ushort4*)&WxS[i][j0r];
      ushort4 wb = *(const ushort4*)&WxS[i][j0r + 4];
      ushort4 wc = *(const ushort4*)&WxS[i][j0r + 8];
      float w12[12] = {bfu(wa.x), bfu(wa.y), bfu(wa.z), bfu(wa.w),
                       bfu(wb.x), bfu(wb.y), bfu(wb.z), bfu(wb.w),
                       bfu(wc.x), bfu(wc.y), bfu(wc.z), bfu(wc.w)};
      float cv[4];
#pragma unroll
      for (int q = 0; q < 4; ++q) cv[q] = bfu(catS[rw * 4 + q][i]);
#pragma unroll
      for (int q = 0; q < 4; ++q)
#pragma unroll
        for (int m = 0; m < 12; ++m) acc[q][m] += cv[q] * w12[m];
    }
#pragma unroll
    for (int q = 0; q < 4; ++q) {
      int n = tile * 64 + rw * 4 + q;
      if (n < 800) {
        int R = b * 800 + n;
#pragma unroll
        for (int m = 0; m < 12; ++m) {
          float v = acc[q][m] + ldc(bx, ((size_t)t * N_ + n) * C_ + jj0 + m);
          xfrag_store(xfrag, R, ty, j0r + m, v);
        }
      }
    }
  }
}

// ---------------- convx body (y >= 11, t = y-11) ---------------------------
template <typename TI>
__device__ __forceinline__ void convx_body(
    float (*tpw)[KW_][2], float (*cw)[KW_][48], float (*preS)[48], float (*Wlx)[144],
    int t,
    const TI* x, const TI* T,
    const TI* conv1_w, const TI* conv1_b,
    const TI* lwz, const TI* lwr, const TI* lwh,
    const TI* lbz, const TI* lbr, const TI* lbh,
    bf16* xfrag) {
  int tile = blockIdx.x, b = blockIdx.z;
  int tid = threadIdx.x;
  int rw = tid / 12, jl = tid % 12;

#pragma unroll 7
  for (int p = 0; p < 7; ++p) {
    int e = tid + p * 192;
    int f = e / (KW_ * 48), rem = e % (KW_ * 48), k = rem / 48, c = rem % 48;
    cw[f][k][c] = ldc(conv1_w, (c * F_ + f) * KW_ + k);
  }
#pragma unroll 10
  for (int p = 0; p < 10; ++p) {
    int e = tid + p * 192;
    if (e < 64 * KW_ * 2) {
      int rr = e / (KW_ * 2), rem = e % (KW_ * 2), k = rem / 2, f = rem % 2;
      int n = tile * 64 + rr; if (n > 799) n = 799;
      int tau = t + k;
      float v;
      if (tau < TIN_) v = ldc(x, ((size_t)(b * TIN_ + tau) * N_ + n) * F_ + f);
      else if (tau < TIN_ + TP_) v = (f == 0) ? 0.f : ldc(T, (size_t)(b * TP_ + (tau - TIN_)) * N_ + n);
      else v = ldc(x, ((size_t)(b * TIN_ + 0) * N_ + n) * F_ + f);
      tpw[rr][k][f] = v;
    }
  }
#pragma unroll 8
  for (int p = 0; p < 36; ++p) {
    int e = tid + p * 192;
    int i = e / 144, jg = e % 144, g = jg / 48, j = jg % 48;
    const TI* w = (g == 0) ? lwz : (g == 1) ? lwr : lwh;
    Wlx[i][jg] = ldc(w, ((size_t)t * 96 + i) * 48 + j);
  }
  __syncthreads();
  {
    int c0 = jl * 4;
    float acc[4][4];
#pragma unroll
    for (int q = 0; q < 4; ++q)
#pragma unroll
      for (int m = 0; m < 4; ++m) acc[q][m] = ldc(conv1_b, c0 + m);
#pragma unroll
    for (int f = 0; f < 2; ++f)
      for (int k = 0; k < KW_; ++k) {
        const float4 w4 = *(const float4*)&cw[f][k][c0];
        float wv[4] = {w4.x, w4.y, w4.z, w4.w};
#pragma unroll
        for (int q = 0; q < 4; ++q) {
          float tv = tpw[rw * 4 + q][k][f];
#pragma unroll
          for (int m = 0; m < 4; ++m) acc[q][m] += tv * wv[m];
        }
      }
#pragma unroll
    for (int q = 0; q < 4; ++q)
      *(float4*)&preS[rw * 4 + q][c0] = make_float4(acc[q][0], acc[q][1], acc[q][2], acc[q][3]);
  }
  __syncthreads();
  {
    int j0r = jl * 12;
    int g = j0r / 48, jj0 = j0r % 48;
    const TI* bx = (g == 0) ? lbz : (g == 1) ? lbr : lbh;
    float acc[4][12];
#pragma unroll
    for (int q = 0; q < 4; ++q)
#pragma unroll
      for (int m = 0; m < 12; ++m) acc[q][m] = 0.f;
    for (int i = 0; i < 48; ++i) {
      const float4 wa = *(const float4*)&Wlx[i][j0r];
      const float4 wb = *(const float4*)&Wlx[i][j0r + 4];
      const float4 wc = *(const float4*)&Wlx[i][j0r + 8];
      float w12[12] = {wa.x, wa.y, wa.z, wa.w, wb.x, wb.y, wb.z, wb.w, wc.x, wc.y, wc.z, wc.w};
      float pv[4];
#pragma unroll
      for (int q = 0; q < 4; ++q) pv[q] = preS[rw * 4 + q][i];
#pragma unroll
      for (int q = 0; q < 4; ++q)
#pragma unroll
        for (int m = 0; m < 12; ++m) acc[q][m] += pv[q] * w12[m];
    }
#pragma unroll
    for (int q = 0; q < 4; ++q) {
      int n = tile * 64 + rw * 4 + q;
      if (n < 800) {
        int R = b * 800 + n;
#pragma unroll
        for (int m = 0; m < 12; ++m) {
          float v = acc[q][m] + ldc(bx, ((size_t)t * N_ + n) * C_ + jj0 + m);
          xfrag_store(xfrag, R, 11 + t, j0r + m, v);
        }
      }
    }
  }
}

// ---------------- Kernel CD: merged projx (y<11) + convx (y>=11) ----------
__global__ __launch_bounds__(192) void k_xparts(
    const int* dtf, const bf16* att_t, const bf16* att_st,
    const void* Wpt, const void* bpt, const void* Wps, const void* bps,
    const void* xwz, const void* xwr, const void* xwh,
    const void* xbz, const void* xbr, const void* xbh,
    const void* x, const void* T, const void* cw_, const void* cb,
    const void* lwz, const void* lwr, const void* lwh,
    const void* lbz, const void* lbr, const void* lbh, bf16* xfrag) {
  __shared__ __align__(16) char smem[62464];
  if (blockIdx.y < 11) {
    auto raw  = (unsigned short(*)[96])smem;                  // 12288 B
    auto WpS  = (unsigned short(*)[48][48])(smem + 12288);    //  9216 B
    auto WxS  = (unsigned short(*)[144])(smem + 21504);       // 27648 B
    auto catS = (unsigned short(*)[104])(smem + 49152);       // 13312 B
    if (*dtf)
      projx_body<float>(raw, WpS, WxS, catS, att_t, att_st,
                        (const float*)Wpt, (const float*)bpt, (const float*)Wps,
                        (const float*)bps, (const float*)xwz, (const float*)xwr,
                        (const float*)xwh, (const float*)xbz, (const float*)xbr,
                        (const float*)xbh, xfrag);
    else
      projx_body<bf16>(raw, WpS, WxS, catS, att_t, att_st,
                       (const bf16*)Wpt, (const bf16*)bpt, (const bf16*)Wps,
                       (const bf16*)bps, (const bf16*)xwz, (const bf16*)xwr,
                       (const bf16*)xwh, (const bf16*)xbz, (const bf16*)xbr,
                       (const bf16*)xbh, xfrag);
  } else {
    int t = blockIdx.y - 11;
    auto tpw  = (float(*)[KW_][2])smem;                       //  7168 B
    auto cw   = (float(*)[KW_][48])(smem + 7168);             //  5376 B
    auto preS = (float(*)[48])(smem + 12544);                 // 12288 B
    auto Wlx  = (float(*)[144])(smem + 24832);                // 27648 B
    if (*dtf)
      convx_body<float>(tpw, cw, preS, Wlx, t,
                        (const float*)x, (const float*)T, (const float*)cw_, (const float*)cb,
                        (const float*)lwz, (const float*)lwr, (const float*)lwh,
                        (const float*)lbz, (const float*)lbr, (const float*)lbh, xfrag);
    else
      convx_body<bf16>(tpw, cw, preS, Wlx, t,
                       (const bf16*)x, (const bf16*)T, (const bf16*)cw_, (const bf16*)cb,
                       (const bf16*)lwz, (const bf16*)lwr, (const bf16*)lwh,
                       (const bf16*)lbz, (const bf16*)lbr, (const bf16*)lbh, xfrag);
  }
}

// ---------------- Kernel E: MFMA GRU v8 — forced register double-buffer ---
// 100 blocks x 64 thr (1 wave = 16 rows), __launch_bounds__(64,1) frees the
// full VGPR budget so BOTH weight sets live in registers. 2-step-unrolled
// loop: even steps use set A (loading B), odd use B (loading A) — every
// array index compile-time, no rotation, loads issue a full phase early.
template <bool PF, typename TO>
__device__ __forceinline__ void gru_step(
    int step, int cl, int cg, int b, int n0,
    s8b (&WZc)[3][2], s8b (&WRc)[3][2], s8b (&WHc)[3][2],
    s8b (&WZn)[3][2], s8b (&WRn)[3][2], s8b (&WHn)[3][2],
    ushort4 (&cx)[9], const unsigned short* xg, const unsigned short* pwb,
    unsigned short* hT, unsigned short* rhT,
    float (&ho)[3][4], const float (&wo)[3], float bo, TO* out) {
  s8b hA0 = *(const s8b*)&hT[cl * 72 + cg * 8];
  s8b hA1 = *(const s8b*)&hT[cl * 72 + 32 + cg * 8];
  f4 az[3], ar[3];
#pragma unroll
  for (int nt = 0; nt < 3; ++nt) {
    f4 cz = {bfu(cx[nt].x), bfu(cx[nt].y), bfu(cx[nt].z), bfu(cx[nt].w)};
    cz = __builtin_amdgcn_mfma_f32_16x16x32_bf16(hA0, WZc[nt][0], cz, 0, 0, 0);
    cz = __builtin_amdgcn_mfma_f32_16x16x32_bf16(hA1, WZc[nt][1], cz, 0, 0, 0);
    az[nt] = cz;
    f4 cr = {bfu(cx[3 + nt].x), bfu(cx[3 + nt].y), bfu(cx[3 + nt].z), bfu(cx[3 + nt].w)};
    cr = __builtin_amdgcn_mfma_f32_16x16x32_bf16(hA0, WRc[nt][0], cr, 0, 0, 0);
    cr = __builtin_amdgcn_mfma_f32_16x16x32_bf16(hA1, WRc[nt][1], cr, 0, 0, 0);
    ar[nt] = cr;
  }
  if (PF) {  // issue next step's z/r weight loads (into the OTHER named set)
    const unsigned short* pb = pwb + (size_t)(step + 1) * 27648 + (size_t)(cg * 16 + cl) * 8;
#pragma unroll
    for (int nt = 0; nt < 3; ++nt)
#pragma unroll
      for (int c = 0; c < 2; ++c) {
        WZn[nt][c] = *(const s8b*)(pb + 0 * 9216 + nt * 3072 + c * 1536);
        WRn[nt][c] = *(const s8b*)(pb + 1 * 9216 + nt * 3072 + c * 1536);
      }
  }
  float xh_[3][4];
#pragma unroll
  for (int nt = 0; nt < 3; ++nt) {
    xh_[nt][0] = bfu(cx[6 + nt].x); xh_[nt][1] = bfu(cx[6 + nt].y);
    xh_[nt][2] = bfu(cx[6 + nt].z); xh_[nt][3] = bfu(cx[6 + nt].w);
  }
  float z[3][4];
#pragma unroll
  for (int nt = 0; nt < 3; ++nt)
#pragma unroll
    for (int r = 0; r < 4; ++r) {
      z[nt][r] = sigm(az[nt][r]);
      float rv = sigm(ar[nt][r]) * ho[nt][r];
      rhT[(cg * 4 + r) * 72 + nt * 16 + cl] = f2u(rv);
    }
  asm volatile("" ::: "memory");  // rh writes before rh A-frag reads (wave DS in-order)
  s8b rA0 = *(const s8b*)&rhT[cl * 72 + cg * 8];
  s8b rA1 = *(const s8b*)&rhT[cl * 72 + 32 + cg * 8];
  f4 ah[3];
#pragma unroll
  for (int nt = 0; nt < 3; ++nt) {
    f4 ch = {xh_[nt][0], xh_[nt][1], xh_[nt][2], xh_[nt][3]};
    ch = __builtin_amdgcn_mfma_f32_16x16x32_bf16(rA0, WHc[nt][0], ch, 0, 0, 0);
    ch = __builtin_amdgcn_mfma_f32_16x16x32_bf16(rA1, WHc[nt][1], ch, 0, 0, 0);
    ah[nt] = ch;
  }
  if (PF) {  // next wh + next x
    const unsigned short* pb = pwb + (size_t)(step + 1) * 27648 + (size_t)(cg * 16 + cl) * 8;
#pragma unroll
    for (int nt = 0; nt < 3; ++nt)
#pragma unroll
      for (int c = 0; c < 2; ++c)
        WHn[nt][c] = *(const s8b*)(pb + 2 * 9216 + nt * 3072 + c * 1536);
  }
  ushort4 nx[9];
  if (PF) {
#pragma unroll
    for (int gn = 0; gn < 9; ++gn)
      nx[gn] = *(const ushort4*)(xg + (step + 1) * 2304 + gn * 256 + (cg * 16 + cl) * 4);
  }
  float pout[4] = {0.f, 0.f, 0.f, 0.f};
#pragma unroll
  for (int nt = 0; nt < 3; ++nt)
#pragma unroll
    for (int r = 0; r < 4; ++r) {
      float hn = (1.f - z[nt][r]) * ho[nt][r] + z[nt][r] * tanh_(ah[nt][r]);
      ho[nt][r] = hn;
      hT[(cg * 4 + r) * 72 + nt * 16 + cl] = f2u(hn);
      pout[r] += hn * wo[nt];
    }
  if (step >= 11) {
#pragma unroll
    for (int r = 0; r < 4; ++r) {
      float p = pout[r];
      p += __shfl_xor(p, 1);
      p += __shfl_xor(p, 2);
      p += __shfl_xor(p, 4);
      p += __shfl_xor(p, 8);
      if (cl == 0)
        sto(out, ((size_t)b * TP_ + (step - 11)) * N_ + n0 + cg * 4 + r, p + bo);
    }
  }
  if (PF) {
#pragma unroll
    for (int gn = 0; gn < 9; ++gn) cx[gn] = nx[gn];
  }
  asm volatile("" ::: "memory");  // h writes before next-step reads
}

template <typename TI, typename TO>
__device__ __forceinline__ void gru8_body(
    unsigned short* hT, unsigned short* rhT,
    const unsigned short* xfrag, const unsigned short* pwb,
    const TI* Wout, const TI* bout, TO* out) {
  int l = threadIdx.x;          // 64
  int cg = l >> 4, cl = l & 15;
  int blk = blockIdx.x;
  int b = blk / 50;
  int n0 = (blk % 50) * 16;

  for (int e = l; e < 1152; e += 64) { hT[e] = 0; rhT[e] = 0; }
  float wo[3];
  float bo = ldc(bout, 0);
#pragma unroll
  for (int nt = 0; nt < 3; ++nt) wo[nt] = ldc(Wout, nt * 16 + cl);
  float ho[3][4];
#pragma unroll
  for (int nt = 0; nt < 3; ++nt)
#pragma unroll
    for (int r = 0; r < 4; ++r) ho[nt][r] = 0.f;

  const unsigned short* xg = xfrag + (size_t)blk * 21 * 2304;
  s8b WA_z[3][2], WA_r[3][2], WA_h[3][2];
  s8b WB_z[3][2], WB_r[3][2], WB_h[3][2];
  ushort4 cx[9];
  {  // step-0 weights into A, step-0 x
    const unsigned short* pb = pwb + (size_t)l * 8;
#pragma unroll
    for (int nt = 0; nt < 3; ++nt)
#pragma unroll
      for (int c = 0; c < 2; ++c) {
        WA_z[nt][c] = *(const s8b*)(pb + 0 * 9216 + nt * 3072 + c * 1536);
        WA_r[nt][c] = *(const s8b*)(pb + 1 * 9216 + nt * 3072 + c * 1536);
        WA_h[nt][c] = *(const s8b*)(pb + 2 * 9216 + nt * 3072 + c * 1536);
      }
#pragma unroll
    for (int gn = 0; gn < 9; ++gn)
      cx[gn] = *(const ushort4*)(xg + gn * 256 + l * 4);
  }
  asm volatile("" ::: "memory");  // hT zero-fill ordered before A-frag reads

#pragma unroll 1
  for (int s2 = 0; s2 < 10; ++s2) {
    gru_step<true>(2 * s2, cl, cg, b, n0, WA_z, WA_r, WA_h, WB_z, WB_r, WB_h,
                   cx, xg, pwb, hT, rhT, ho, wo, bo, out);
    gru_step<true>(2 * s2 + 1, cl, cg, b, n0, WB_z, WB_r, WB_h, WA_z, WA_r, WA_h,
                   cx, xg, pwb, hT, rhT, ho, wo, bo, out);
  }
  gru_step<false>(20, cl, cg, b, n0, WA_z, WA_r, WA_h, WB_z, WB_r, WB_h,
                  cx, xg, pwb, hT, rhT, ho, wo, bo, out);
}
__global__ __launch_bounds__(64, 1) void k_gru8(
    const int* dtf, const bf16* xfrag, const bf16* pwb,
    const void* Wout, const void* bout, void* out) {
  __shared__ alignas(16) unsigned short hT[1152];    // [16][72]
  __shared__ alignas(16) unsigned short rhT[1152];
  if (*dtf)
    gru8_body<float, float>(hT, rhT,
                            (const unsigned short*)xfrag, (const unsigned short*)pwb,
                            (const float*)Wout, (const float*)bout, (float*)out);
  else
    gru8_body<bf16, bf16>(hT, rhT,
                          (const unsigned short*)xfrag, (const unsigned short*)pwb,
                          (const bf16*)Wout, (const bf16*)bout, (bf16*)out);
}

// ---------------------------------------------------------------------------
extern "C" void kernel_launch(void* const* d_in, const int* in_sizes, int n_in,
                              void* d_out, int out_size, void* d_ws, size_t ws_size,
                              hipStream_t stream) {
  (void)in_sizes; (void)n_in; (void)out_size; (void)ws_size;
  const void* x       = d_in[0];
  const void* T       = d_in[1];
  const void* Wq_t    = d_in[3];
  const void* Wk_t    = d_in[4];
  const void* Wv_t    = d_in[5];
  const void* Wq_st   = d_in[6];
  const void* Wk_st   = d_in[7];
  const void* Wv_st   = d_in[8];
  const void* bq_t    = d_in[9];
  const void* bk_t    = d_in[10];
  const void* bv_t    = d_in[11];
  const void* bq_st   = d_in[12];
  const void* bk_st   = d_in[13];
  const void* bv_st   = d_in[14];
  const void* conv1_w = d_in[15];
  const void* conv1_b = d_in[16];
  const void* Wproj_t = d_in[17];
  const void* bproj_t = d_in[18];
  const void* Wproj_st= d_in[19];
  const void* bproj_st= d_in[20];
  const void* xhr_wz  = d_in[21];
  const void* xhr_wr  = d_in[22];
  const void* xhr_wh  = d_in[23];
  const void* xhr_bz  = d_in[24];
  const void* xhr_br  = d_in[25];
  const void* xhr_bh  = d_in[26];
  const void* last_wz = d_in[27];
  const void* last_wr = d_in[28];
  const void* last_wh = d_in[29];
  const void* last_bz = d_in[30];
  const void* last_br = d_in[31];
  const void* last_bh = d_in[32];
  const void* Wout    = d_in[33];
  const void* bout    = d_in[34];

  // ws layout (~14.2 MB; 14.75 MB proven safe earlier)
  char* wsb = (char*)d_ws;
  int* dtf     = (int*)wsb;                              // 256 B
  bf16* att_t  = (bf16*)(wsb + 256);                     // 2*11*800*48
  bf16* att_st = att_t + (size_t)2 * 11 * 800 * 48;
  bf16* xfrag  = att_st + (size_t)2 * 11 * 800 * 48;     // 100*21*9*64*4 elems
  bf16* pwb    = xfrag + (size_t)100 * 21 * 9 * 64 * 4;  // 21*27648

  k_detect<<<1, 64, 0, stream>>>((const unsigned int*)x, dtf);
  k_pack<<<(21 * 27648 + 255) / 256, 256, 0, stream>>>(
      dtf, xhr_wz, xhr_wr, xhr_wh, last_wz, last_wr, last_wh, pwb);
  {
    int total = B_ * (TIN_ - 1) * H_ * N_;
    k_temporal<<<(total + 255) / 256, 256, 0, stream>>>(
        dtf, x, Wq_t, Wk_t, Wv_t, bq_t, bk_t, bv_t, att_t);
  }
  k_spatial2<<<dim3(ST_TILES, 11, 2), 832, 0, stream>>>(
      dtf, x, Wq_st, Wk_st, Wv_st, bq_st, bk_st, bv_st, att_st);
  k_xparts<<<dim3(13, 21, 2), 192, 0, stream>>>(
      dtf, att_t, att_st, Wproj_t, bproj_t, Wproj_st, bproj_st,
      xhr_wz, xhr_wr, xhr_wh, xhr_bz, xhr_br, xhr_bh,
      x, T, conv1_w, conv1_b, last_wz, last_wr, last_wh,
      last_bz, last_br, last_bh, xfrag);
  k_gru8<<<100, 64, 0, stream>>>(
      dtf, xfrag, pwb, Wout, bout, d_out);
}

// Round 13
// 130.905 us; speedup vs baseline: 1.7380x; 1.2875x over previous
//
#include <hip/hip_runtime.h>
#include <hip/hip_bf16.h>

typedef __hip_bfloat16 bf16;
typedef __attribute__((ext_vector_type(8))) short s8b;   // 8 bf16 (4 VGPR)
typedef __attribute__((ext_vector_type(4))) float f4;    // MFMA C/D

#define B_ 2
#define TIN_ 12
#define N_ 800
#define F_ 2
#define H_ 6
#define D_ 8
#define C_ 48
#define TP_ 10
#define KW_ 14
#define SCALE 0.35355339059327373f  // 1/sqrt(8)
#define LOG2E 1.4426950408889634f

__device__ __forceinline__ float sigm(float x) { return 1.0f / (1.0f + __expf(-x)); }
__device__ __forceinline__ float tanh_(float x) {
  float e = __expf(-2.0f * x);
  return 2.0f / (1.0f + e) - 1.0f;
}
__device__ __forceinline__ float exp2_(float x) { return __builtin_amdgcn_exp2f(x); }
__device__ __forceinline__ float bfu(unsigned short u) {
  return __uint_as_float((unsigned)u << 16);
}
__device__ __forceinline__ unsigned short f2u(float v) {
  return __bfloat16_as_ushort(__float2bfloat16(v));
}
__device__ __forceinline__ float ldc(const float* p, size_t i) { return p[i]; }
__device__ __forceinline__ float ldc(const bf16* p, size_t i) { return __bfloat162float(p[i]); }
__device__ __forceinline__ void sto(float* p, size_t i, float v) { p[i] = v; }
__device__ __forceinline__ void sto(bf16* p, size_t i, float v) { p[i] = __float2bfloat16(v); }

// ---------------- Kernel 0: dtype detector --------------------------------
__global__ void k_detect(const unsigned int* __restrict__ xw, int* __restrict__ flag) {
  int lane = threadIdx.x;  // 64
  unsigned int w = xw[lane];
  int e = (w >> 7) & 0xFF;  // exponent of LOW bf16 slot
  int bad = ((e >= 1 && e < 96) || (e > 150)) ? 1 : 0;
  unsigned long long m = __ballot(bad);
  if (lane == 0) *flag = (__popcll(m) >= 16) ? 1 : 0;
}

// ---------------- Kernel P: pack recurrent weights to MFMA B-fragments ----
template <typename TI>
__device__ __forceinline__ void pack_body(
    const TI* xwz, const TI* xwr, const TI* xwh,
    const TI* lwz, const TI* lwr, const TI* lwh, bf16* pwb) {
  int gid = blockIdx.x * 256 + threadIdx.x;
  const int total = 21 * 27648;
  if (gid >= total) return;
  int step = gid / 27648, r = gid % 27648;
  int g = r / 9216;  r %= 9216;
  int nt = r / 3072; r %= 3072;
  int c = r / 1536;  r %= 1536;
  int lane = r / 8, j = r % 8;
  int k = 32 * c + (lane >> 4) * 8 + j;
  int n = nt * 16 + (lane & 15);
  float v = 0.f;
  if (k < 48) {
    if (step < 11) {
      int t = step + 1;
      const TI* w = (g == 0) ? xwz : (g == 1) ? xwr : xwh;
      v = ldc(w, ((size_t)t * 144 + 96 + k) * 48 + n);
    } else {
      int t = step - 11;
      const TI* w = (g == 0) ? lwz : (g == 1) ? lwr : lwh;
      v = ldc(w, ((size_t)t * 96 + 48 + k) * 48 + n);
    }
  }
  pwb[gid] = __float2bfloat16(v);
}
__global__ void k_pack(const int* dtf, const void* xwz, const void* xwr, const void* xwh,
                       const void* lwz, const void* lwr, const void* lwh, bf16* pwb) {
  if (*dtf)
    pack_body<float>((const float*)xwz, (const float*)xwr, (const float*)xwh,
                     (const float*)lwz, (const float*)lwr, (const float*)lwh, pwb);
  else
    pack_body<bf16>((const bf16*)xwz, (const bf16*)xwr, (const bf16*)xwh,
                    (const bf16*)lwz, (const bf16*)lwr, (const bf16*)lwh, pwb);
}

// ---------------- Kernel A: temporal causal attention (t=1..11) -----------
template <typename TI>
__device__ __forceinline__ void temporal_body(
    const TI* x, const TI* Wq, const TI* Wk, const TI* Wv,
    const TI* bq, const TI* bk, const TI* bv, bf16* att_t) {
  int gid = blockIdx.x * blockDim.x + threadIdx.x;
  const int total = B_ * (TIN_ - 1) * H_ * N_;
  if (gid >= total) return;
  int n = gid % N_;
  int r = gid / N_;
  int h = r % H_;  r /= H_;
  int t = (r % (TIN_ - 1)) + 1;
  int b = r / (TIN_ - 1);

  float wq[F_][D_], wk[F_][D_], wv[F_][D_], bqv[D_], bkv[D_], bvv[D_];
#pragma unroll
  for (int f = 0; f < F_; ++f)
#pragma unroll
    for (int d = 0; d < D_; ++d) {
      wq[f][d] = ldc(Wq, (h * F_ + f) * D_ + d);
      wk[f][d] = ldc(Wk, (h * F_ + f) * D_ + d);
      wv[f][d] = ldc(Wv, (h * F_ + f) * D_ + d);
    }
#pragma unroll
  for (int d = 0; d < D_; ++d) {
    bqv[d] = ldc(bq, h * D_ + d);
    bkv[d] = ldc(bk, h * D_ + d);
    bvv[d] = ldc(bv, h * D_ + d);
  }
  float xt0 = ldc(x, ((b * TIN_ + t) * N_ + n) * F_ + 0);
  float xt1 = ldc(x, ((b * TIN_ + t) * N_ + n) * F_ + 1);
  float q[D_];
#pragma unroll
  for (int d = 0; d < D_; ++d) q[d] = xt0 * wq[0][d] + xt1 * wq[1][d] + bqv[d];

  float sc[TIN_];
  float mx = -1e30f;
#pragma unroll
  for (int s = 0; s < TIN_; ++s) {
    float xs0 = ldc(x, ((b * TIN_ + s) * N_ + n) * F_ + 0);
    float xs1 = ldc(x, ((b * TIN_ + s) * N_ + n) * F_ + 1);
    float dot = 0.f;
#pragma unroll
    for (int d = 0; d < D_; ++d)
      dot += q[d] * (xs0 * wk[0][d] + xs1 * wk[1][d] + bkv[d]);
    dot *= SCALE;
    sc[s] = (s <= t) ? dot : -1e30f;
    mx = fmaxf(mx, sc[s]);
  }
  float sum = 0.f;
#pragma unroll
  for (int s = 0; s < TIN_; ++s) {
    float p = __expf(sc[s] - mx);
    sc[s] = p;
    sum += p;
  }
  float inv = 1.0f / sum;
  float acc[D_];
#pragma unroll
  for (int d = 0; d < D_; ++d) acc[d] = 0.f;
#pragma unroll
  for (int s = 0; s < TIN_; ++s) {
    float xs0 = ldc(x, ((b * TIN_ + s) * N_ + n) * F_ + 0);
    float xs1 = ldc(x, ((b * TIN_ + s) * N_ + n) * F_ + 1);
#pragma unroll
    for (int d = 0; d < D_; ++d)
      acc[d] += sc[s] * (xs0 * wv[0][d] + xs1 * wv[1][d] + bvv[d]);
  }
  bf16* o = att_t + ((size_t)((b * 11 + (t - 1)) * N_ + n)) * C_ + h * D_;
#pragma unroll
  for (int d = 0; d < D_; ++d) o[d] = __float2bfloat16(acc[d] * inv);
}
__global__ void k_temporal(const int* dtf, const void* x, const void* Wq, const void* Wk,
                           const void* Wv, const void* bq, const void* bk, const void* bv,
                           bf16* att_t) {
  if (*dtf)
    temporal_body<float>((const float*)x, (const float*)Wq, (const float*)Wk, (const float*)Wv,
                         (const float*)bq, (const float*)bk, (const float*)bv, att_t);
  else
    temporal_body<bf16>((const bf16*)x, (const bf16*)Wq, (const bf16*)Wk, (const bf16*)Wv,
                        (const bf16*)bq, (const bf16*)bk, (const bf16*)bv, att_t);
}

// ---------------- Kernel B: spatial attention, rank-2 form ----------------
#define ST_TILES 8
#define ST_ROWS 100
#define ST_MS 8
#define ST_MLEN 100
template <typename TI>
__device__ __forceinline__ void spatial2_body(
    float2* xs, float (*M)[9], float (*Vw)[3][D_], float (*pt)[ST_ROWS][19],
    const TI* x, const TI* Wq, const TI* Wk, const TI* Wv,
    const TI* bq, const TI* bk, const TI* bv, bf16* att_st) {
  int tile = blockIdx.x, ty = blockIdx.y, b = blockIdx.z;
  int t = ty + 1;
  int tid = threadIdx.x;

  for (int m = tid; m < N_; m += 832)
    xs[m] = make_float2(ldc(x, ((b * TIN_ + t) * N_ + m) * F_ + 0),
                        ldc(x, ((b * TIN_ + t) * N_ + m) * F_ + 1));
  if (tid < 54) {
    int h = tid / 9, e = tid % 9, a = e / 3, bb = e % 3;
    float acc = 0.f;
    for (int d = 0; d < 8; ++d) {
      float qa = (a == 0) ? ldc(Wq, (h * 2 + 0) * 8 + d)
               : (a == 1) ? ldc(Wq, (h * 2 + 1) * 8 + d) : ldc(bq, h * 8 + d);
      float kb = (bb == 0) ? ldc(Wk, (h * 2 + 0) * 8 + d)
               : (bb == 1) ? ldc(Wk, (h * 2 + 1) * 8 + d) : ldc(bk, h * 8 + d);
      acc += qa * kb;
    }
    M[h][e] = acc * SCALE * LOG2E;
  }
  if (tid >= 64 && tid < 64 + 144) {
    int e = tid - 64;
    int h = e / 24, a = (e % 24) / 8, d = e % 8;
    Vw[h][a][d] = (a == 0) ? ldc(Wv, (h * 2 + 0) * 8 + d)
                : (a == 1) ? ldc(Wv, (h * 2 + 1) * 8 + d) : ldc(bv, h * 8 + d);
  }
  __syncthreads();
  if (tid < ST_ROWS * ST_MS) {
    int ms = tid / ST_ROWS, nl = tid % ST_ROWS;
    int n = tile * ST_ROWS + nl;
    float x0 = xs[n].x, x1 = xs[n].y;
    float A[6], Bc[6], Cc[6];
#pragma unroll
    for (int h = 0; h < 6; ++h) {
      A[h]  = M[h][0] * x0 + M[h][3] * x1 + M[h][6];
      Bc[h] = M[h][1] * x0 + M[h][4] * x1 + M[h][7];
      Cc[h] = M[h][2] * x0 + M[h][5] * x1 + M[h][8];
    }
    float Sp[6] = {0, 0, 0, 0, 0, 0}, S0[6] = {0, 0, 0, 0, 0, 0}, S1[6] = {0, 0, 0, 0, 0, 0};
    for (int m = ms * ST_MLEN; m < ms * ST_MLEN + ST_MLEN; ++m) {
      float2 xm = xs[m];
#pragma unroll
      for (int h = 0; h < 6; ++h) {
        float p = exp2_(A[h] * xm.x + Bc[h] * xm.y + Cc[h]);
        Sp[h] += p;
        S0[h] += p * xm.x;
        S1[h] += p * xm.y;
      }
    }
#pragma unroll
    for (int h = 0; h < 6; ++h) {
      pt[ms][nl][h * 3 + 0] = Sp[h];
      pt[ms][nl][h * 3 + 1] = S0[h];
      pt[ms][nl][h * 3 + 2] = S1[h];
    }
  }
  __syncthreads();
  if (tid < ST_ROWS) {
    int n = tile * ST_ROWS + tid;
    bf16* o = att_st + ((size_t)((b * 11 + ty) * N_ + n)) * C_;
#pragma unroll
    for (int h = 0; h < 6; ++h) {
      float Sp = 0.f, S0 = 0.f, S1 = 0.f;
#pragma unroll
      for (int ms = 0; ms < ST_MS; ++ms) {
        Sp += pt[ms][tid][h * 3 + 0];
        S0 += pt[ms][tid][h * 3 + 1];
        S1 += pt[ms][tid][h * 3 + 2];
      }
      float inv = 1.f / Sp;
#pragma unroll
      for (int d = 0; d < 8; ++d)
        o[h * 8 + d] = __float2bfloat16((S0 * Vw[h][0][d] + S1 * Vw[h][1][d] + Sp * Vw[h][2][d]) * inv);
    }
  }
}
__global__ __launch_bounds__(832) void k_spatial2(
    const int* dtf, const void* x, const void* Wq, const void* Wk, const void* Wv,
    const void* bq, const void* bk, const void* bv, bf16* att_st) {
  __shared__ float2 xs[N_];
  __shared__ float M[H_][9];
  __shared__ float Vw[H_][3][D_];
  __shared__ float pt[ST_MS][ST_ROWS][19];
  if (*dtf)
    spatial2_body<float>(xs, M, Vw, pt,
                         (const float*)x, (const float*)Wq, (const float*)Wk, (const float*)Wv,
                         (const float*)bq, (const float*)bk, (const float*)bv, att_st);
  else
    spatial2_body<bf16>(xs, M, Vw, pt,
                        (const bf16*)x, (const bf16*)Wq, (const bf16*)Wk, (const bf16*)Wv,
                        (const bf16*)bq, (const bf16*)bk, (const bf16*)bv, att_st);
}

// ---------------- Kernel CD v2: MFMA xparts --------------------------------
// grid (13, 21, 2) x 192 thr (3 waves). y<11: projx path; y>=11: convx path.
// A-frags from LDS (pitch 72/104 -> 2-way max); B-frags built per-lane from
// global weights (predicated, L2-resident); C init = biases; D stored as one
// coalesced 8B ushort4 per tile directly in xfrag fragment order.

// projx: phase1 cat(64x96)=[att_t@Wpt | att_st@Wps]+bp; phase2 x-parts.
template <typename TI>
__device__ __forceinline__ void projx2_body(
    unsigned short (*rawT)[72], unsigned short (*rawS)[72], unsigned short (*catS)[104],
    const bf16* att_t, const bf16* att_st,
    const TI* Wpt, const TI* bpt, const TI* Wps, const TI* bps,
    const TI* xwz, const TI* xwr, const TI* xwh,
    const TI* xbz, const TI* xbr, const TI* xbh,
    bf16* xfrag) {
  int tile = blockIdx.x, ty = blockIdx.y, b = blockIdx.z;
  int t = ty + 1;
  int tid = threadIdx.x;
  int wv = tid >> 6, l = tid & 63;
  int cg = l >> 4, cl = l & 15;

  for (int e = tid; e < 64 * 72; e += 192) {   // stage att rows, cols>=48 zero
    int rr = e / 72, c = e % 72;
    int n = tile * 64 + rr; if (n > 799) n = 799;
    size_t base = ((size_t)((b * 11 + ty) * N_ + n)) * C_;
    rawT[rr][c] = (c < 48) ? __bfloat16_as_ushort(att_t[base + c]) : (unsigned short)0;
    rawS[rr][c] = (c < 48) ? __bfloat16_as_ushort(att_st[base + c]) : (unsigned short)0;
  }
  __syncthreads();
  // ---- phase 1: wave wv handles nt = 2wv, 2wv+1 (cat cols nt*16..+15) ----
#pragma unroll
  for (int q = 0; q < 2; ++q) {
    int nt = 2 * wv + q;
    int half = nt / 3;
    int ncol = (nt - half * 3) * 16 + cl;   // 0..47
    float bias = half ? ldc(bps, ncol) : ldc(bpt, ncol);
    s8b Bf0, Bf1;
#pragma unroll
    for (int j = 0; j < 8; ++j) {
      int k0 = cg * 8 + j;
      int k1 = 32 + cg * 8 + j;
      Bf0[j] = (short)f2u(half ? ldc(Wps, (size_t)k0 * 48 + ncol)
                               : ldc(Wpt, (size_t)k0 * 48 + ncol));
      Bf1[j] = (k1 < 48) ? (short)f2u(half ? ldc(Wps, (size_t)k1 * 48 + ncol)
                                           : ldc(Wpt, (size_t)k1 * 48 + ncol))
                         : (short)0;
    }
    unsigned short (*raw)[72] = half ? rawS : rawT;
#pragma unroll
    for (int mt = 0; mt < 4; ++mt) {
      s8b A0 = *(const s8b*)&raw[mt * 16 + cl][cg * 8];
      s8b A1 = *(const s8b*)&raw[mt * 16 + cl][32 + cg * 8];
      f4 acc = {bias, bias, bias, bias};
      acc = __builtin_amdgcn_mfma_f32_16x16x32_bf16(A0, Bf0, acc, 0, 0, 0);
      acc = __builtin_amdgcn_mfma_f32_16x16x32_bf16(A1, Bf1, acc, 0, 0, 0);
#pragma unroll
      for (int r = 0; r < 4; ++r)
        catS[mt * 16 + cg * 4 + r][nt * 16 + cl] = f2u(acc[r]);
    }
  }
  __syncthreads();
  // ---- phase 2: wave wv handles nt = 3wv..3wv+2 (out cols nt*16..+15) ----
#pragma unroll
  for (int q = 0; q < 3; ++q) {
    int nt = 3 * wv + q;
    int g = nt / 3;
    int jj = (nt - g * 3) * 16 + cl;        // 0..47
    const TI* wx = (g == 0) ? xwz : (g == 1) ? xwr : xwh;
    const TI* bx = (g == 0) ? xbz : (g == 1) ? xbr : xbh;
    s8b Bf[3];
#pragma unroll
    for (int c = 0; c < 3; ++c)
#pragma unroll
      for (int j = 0; j < 8; ++j) {
        int k = c * 32 + cg * 8 + j;
        Bf[c][j] = (short)f2u(ldc(wx, ((size_t)t * 144 + k) * 48 + jj));
      }
#pragma unroll
    for (int mt = 0; mt < 4; ++mt) {
      int nbase = tile * 64 + mt * 16;
      if (nbase >= 800) continue;
      s8b A0 = *(const s8b*)&catS[mt * 16 + cl][cg * 8];
      s8b A1 = *(const s8b*)&catS[mt * 16 + cl][32 + cg * 8];
      s8b A2 = *(const s8b*)&catS[mt * 16 + cl][64 + cg * 8];
      f4 acc;
#pragma unroll
      for (int r = 0; r < 4; ++r)
        acc[r] = ldc(bx, ((size_t)t * N_ + (nbase + cg * 4 + r)) * C_ + jj);
      acc = __builtin_amdgcn_mfma_f32_16x16x32_bf16(A0, Bf[0], acc, 0, 0, 0);
      acc = __builtin_amdgcn_mfma_f32_16x16x32_bf16(A1, Bf[1], acc, 0, 0, 0);
      acc = __builtin_amdgcn_mfma_f32_16x16x32_bf16(A2, Bf[2], acc, 0, 0, 0);
      int grp = b * 50 + tile * 4 + mt;
      size_t idx = ((((size_t)grp * 21 + ty) * 9 + nt) * 64 + l) * 4;
      ushort4 u;
      u.x = f2u(acc[0]); u.y = f2u(acc[1]); u.z = f2u(acc[2]); u.w = f2u(acc[3]);
      *(ushort4*)((unsigned short*)xfrag + idx) = u;
    }
  }
}

// convx: conv1 (VALU, small) -> preS bf16; phase2 MFMA.
template <typename TI>
__device__ __forceinline__ void convx2_body(
    float (*tpw)[KW_][2], float (*cw)[KW_][48], unsigned short (*preS)[72],
    int t, const TI* x, const TI* T,
    const TI* conv1_w, const TI* conv1_b,
    const TI* lwz, const TI* lwr, const TI* lwh,
    const TI* lbz, const TI* lbr, const TI* lbh,
    bf16* xfrag) {
  int tile = blockIdx.x, b = blockIdx.z;
  int tid = threadIdx.x;
  int wv = tid >> 6, l = tid & 63;
  int cg = l >> 4, cl = l & 15;
  int rw = tid / 12, jl = tid % 12;

#pragma unroll 7
  for (int p = 0; p < 7; ++p) {
    int e = tid + p * 192;
    int f = e / (KW_ * 48), rem = e % (KW_ * 48), k = rem / 48, c = rem % 48;
    cw[f][k][c] = ldc(conv1_w, (c * F_ + f) * KW_ + k);
  }
#pragma unroll 10
  for (int p = 0; p < 10; ++p) {
    int e = tid + p * 192;
    if (e < 64 * KW_ * 2) {
      int rr = e / (KW_ * 2), rem = e % (KW_ * 2), k = rem / 2, f = rem % 2;
      int n = tile * 64 + rr; if (n > 799) n = 799;
      int tau = t + k;
      float v;
      if (tau < TIN_) v = ldc(x, ((size_t)(b * TIN_ + tau) * N_ + n) * F_ + f);
      else if (tau < TIN_ + TP_) v = (f == 0) ? 0.f : ldc(T, (size_t)(b * TP_ + (tau - TIN_)) * N_ + n);
      else v = ldc(x, ((size_t)(b * TIN_ + 0) * N_ + n) * F_ + f);
      tpw[rr][k][f] = v;
    }
  }
  for (int e = tid; e < 64 * 24; e += 192)   // zero preS cols 48..71
    preS[e / 24][48 + e % 24] = 0;
  __syncthreads();
  {  // conv: 4 rows x 4 channels per thread
    int c0 = jl * 4;
    float acc[4][4];
#pragma unroll
    for (int qq = 0; qq < 4; ++qq)
#pragma unroll
      for (int m = 0; m < 4; ++m) acc[qq][m] = ldc(conv1_b, c0 + m);
#pragma unroll
    for (int f = 0; f < 2; ++f)
      for (int k = 0; k < KW_; ++k) {
        const float4 w4 = *(const float4*)&cw[f][k][c0];
        float wvv[4] = {w4.x, w4.y, w4.z, w4.w};
#pragma unroll
        for (int qq = 0; qq < 4; ++qq) {
          float tv = tpw[rw * 4 + qq][k][f];
#pragma unroll
          for (int m = 0; m < 4; ++m) acc[qq][m] += tv * wvv[m];
        }
      }
#pragma unroll
    for (int qq = 0; qq < 4; ++qq)
#pragma unroll
      for (int m = 0; m < 4; ++m)
        preS[rw * 4 + qq][c0 + m] = f2u(acc[qq][m]);
  }
  __syncthreads();
  // ---- phase 2: decx = pre(64x48) @ Wl(48x144) + bias ----
#pragma unroll
  for (int q = 0; q < 3; ++q) {
    int nt = 3 * wv + q;
    int g = nt / 3;
    int jj = (nt - g * 3) * 16 + cl;
    const TI* wl = (g == 0) ? lwz : (g == 1) ? lwr : lwh;
    const TI* bl = (g == 0) ? lbz : (g == 1) ? lbr : lbh;
    s8b Bf0, Bf1;
#pragma unroll
    for (int j = 0; j < 8; ++j) {
      int k0 = cg * 8 + j;
      int k1 = 32 + cg * 8 + j;
      Bf0[j] = (short)f2u(ldc(wl, ((size_t)t * 96 + k0) * 48 + jj));
      Bf1[j] = (k1 < 48) ? (short)f2u(ldc(wl, ((size_t)t * 96 + k1) * 48 + jj)) : (short)0;
    }
#pragma unroll
    for (int mt = 0; mt < 4; ++mt) {
      int nbase = tile * 64 + mt * 16;
      if (nbase >= 800) continue;
      s8b A0 = *(const s8b*)&preS[mt * 16 + cl][cg * 8];
      s8b A1 = *(const s8b*)&preS[mt * 16 + cl][32 + cg * 8];
      f4 acc;
#pragma unroll
      for (int r = 0; r < 4; ++r)
        acc[r] = ldc(bl, ((size_t)t * N_ + (nbase + cg * 4 + r)) * C_ + jj);
      acc = __builtin_amdgcn_mfma_f32_16x16x32_bf16(A0, Bf0, acc, 0, 0, 0);
      acc = __builtin_amdgcn_mfma_f32_16x16x32_bf16(A1, Bf1, acc, 0, 0, 0);
      int grp = b * 50 + tile * 4 + mt;
      size_t idx = ((((size_t)grp * 21 + (11 + t)) * 9 + nt) * 64 + l) * 4;
      ushort4 u;
      u.x = f2u(acc[0]); u.y = f2u(acc[1]); u.z = f2u(acc[2]); u.w = f2u(acc[3]);
      *(ushort4*)((unsigned short*)xfrag + idx) = u;
    }
  }
}

__global__ __launch_bounds__(192) void k_xparts(
    const int* dtf, const bf16* att_t, const bf16* att_st,
    const void* Wpt, const void* bpt, const void* Wps, const void* bps,
    const void* xwz, const void* xwr, const void* xwh,
    const void* xbz, const void* xbr, const void* xbh,
    const void* x, const void* T, const void* cw_, const void* cb,
    const void* lwz, const void* lwr, const void* lwh,
    const void* lbz, const void* lbr, const void* lbh, bf16* xfrag) {
  __shared__ __align__(16) char smem[31744];
  if (blockIdx.y < 11) {
    auto rawT = (unsigned short(*)[72])smem;                 //  9216 B
    auto rawS = (unsigned short(*)[72])(smem + 9216);        //  9216 B
    auto catS = (unsigned short(*)[104])(smem + 18432);      // 13312 B
    if (*dtf)
      projx2_body<float>(rawT, rawS, catS, att_t, att_st,
                         (const float*)Wpt, (const float*)bpt, (const float*)Wps,
                         (const float*)bps, (const float*)xwz, (const float*)xwr,
                         (const float*)xwh, (const float*)xbz, (const float*)xbr,
                         (const float*)xbh, xfrag);
    else
      projx2_body<bf16>(rawT, rawS, catS, att_t, att_st,
                        (const bf16*)Wpt, (const bf16*)bpt, (const bf16*)Wps,
                        (const bf16*)bps, (const bf16*)xwz, (const bf16*)xwr,
                        (const bf16*)xwh, (const bf16*)xbz, (const bf16*)xbr,
                        (const bf16*)xbh, xfrag);
  } else {
    int t = blockIdx.y - 11;
    auto tpw  = (float(*)[KW_][2])smem;                      //  7168 B
    auto cw   = (float(*)[KW_][48])(smem + 7168);            //  5376 B
    auto preS = (unsigned short(*)[72])(smem + 12544);       //  9216 B
    if (*dtf)
      convx2_body<float>(tpw, cw, preS, t,
                         (const float*)x, (const float*)T, (const float*)cw_, (const float*)cb,
                         (const float*)lwz, (const float*)lwr, (const float*)lwh,
                         (const float*)lbz, (const float*)lbr, (const float*)lbh, xfrag);
    else
      convx2_body<bf16>(tpw, cw, preS, t,
                        (const bf16*)x, (const bf16*)T, (const bf16*)cw_, (const bf16*)cb,
                        (const bf16*)lwz, (const bf16*)lwr, (const bf16*)lwh,
                        (const bf16*)lbz, (const bf16*)lbr, (const bf16*)lbh, xfrag);
  }
}

// ---------------- Kernel E: MFMA GRU v8 — forced register double-buffer ---
template <bool PF, typename TO>
__device__ __forceinline__ void gru_step(
    int step, int cl, int cg, int b, int n0,
    s8b (&WZc)[3][2], s8b (&WRc)[3][2], s8b (&WHc)[3][2],
    s8b (&WZn)[3][2], s8b (&WRn)[3][2], s8b (&WHn)[3][2],
    ushort4 (&cx)[9], const unsigned short* xg, const unsigned short* pwb,
    unsigned short* hT, unsigned short* rhT,
    float (&ho)[3][4], const float (&wo)[3], float bo, TO* out) {
  s8b hA0 = *(const s8b*)&hT[cl * 72 + cg * 8];
  s8b hA1 = *(const s8b*)&hT[cl * 72 + 32 + cg * 8];
  f4 az[3], ar[3];
#pragma unroll
  for (int nt = 0; nt < 3; ++nt) {
    f4 cz = {bfu(cx[nt].x), bfu(cx[nt].y), bfu(cx[nt].z), bfu(cx[nt].w)};
    cz = __builtin_amdgcn_mfma_f32_16x16x32_bf16(hA0, WZc[nt][0], cz, 0, 0, 0);
    cz = __builtin_amdgcn_mfma_f32_16x16x32_bf16(hA1, WZc[nt][1], cz, 0, 0, 0);
    az[nt] = cz;
    f4 cr = {bfu(cx[3 + nt].x), bfu(cx[3 + nt].y), bfu(cx[3 + nt].z), bfu(cx[3 + nt].w)};
    cr = __builtin_amdgcn_mfma_f32_16x16x32_bf16(hA0, WRc[nt][0], cr, 0, 0, 0);
    cr = __builtin_amdgcn_mfma_f32_16x16x32_bf16(hA1, WRc[nt][1], cr, 0, 0, 0);
    ar[nt] = cr;
  }
  if (PF) {
    const unsigned short* pb = pwb + (size_t)(step + 1) * 27648 + (size_t)(cg * 16 + cl) * 8;
#pragma unroll
    for (int nt = 0; nt < 3; ++nt)
#pragma unroll
      for (int c = 0; c < 2; ++c) {
        WZn[nt][c] = *(const s8b*)(pb + 0 * 9216 + nt * 3072 + c * 1536);
        WRn[nt][c] = *(const s8b*)(pb + 1 * 9216 + nt * 3072 + c * 1536);
      }
  }
  float xh_[3][4];
#pragma unroll
  for (int nt = 0; nt < 3; ++nt) {
    xh_[nt][0] = bfu(cx[6 + nt].x); xh_[nt][1] = bfu(cx[6 + nt].y);
    xh_[nt][2] = bfu(cx[6 + nt].z); xh_[nt][3] = bfu(cx[6 + nt].w);
  }
  float z[3][4];
#pragma unroll
  for (int nt = 0; nt < 3; ++nt)
#pragma unroll
    for (int r = 0; r < 4; ++r) {
      z[nt][r] = sigm(az[nt][r]);
      float rv = sigm(ar[nt][r]) * ho[nt][r];
      rhT[(cg * 4 + r) * 72 + nt * 16 + cl] = f2u(rv);
    }
  asm volatile("" ::: "memory");
  s8b rA0 = *(const s8b*)&rhT[cl * 72 + cg * 8];
  s8b rA1 = *(const s8b*)&rhT[cl * 72 + 32 + cg * 8];
  f4 ah[3];
#pragma unroll
  for (int nt = 0; nt < 3; ++nt) {
    f4 ch = {xh_[nt][0], xh_[nt][1], xh_[nt][2], xh_[nt][3]};
    ch = __builtin_amdgcn_mfma_f32_16x16x32_bf16(rA0, WHc[nt][0], ch, 0, 0, 0);
    ch = __builtin_amdgcn_mfma_f32_16x16x32_bf16(rA1, WHc[nt][1], ch, 0, 0, 0);
    ah[nt] = ch;
  }
  if (PF) {
    const unsigned short* pb = pwb + (size_t)(step + 1) * 27648 + (size_t)(cg * 16 + cl) * 8;
#pragma unroll
    for (int nt = 0; nt < 3; ++nt)
#pragma unroll
      for (int c = 0; c < 2; ++c)
        WHn[nt][c] = *(const s8b*)(pb + 2 * 9216 + nt * 3072 + c * 1536);
  }
  ushort4 nx[9];
  if (PF) {
#pragma unroll
    for (int gn = 0; gn < 9; ++gn)
      nx[gn] = *(const ushort4*)(xg + (step + 1) * 2304 + gn * 256 + (cg * 16 + cl) * 4);
  }
  float pout[4] = {0.f, 0.f, 0.f, 0.f};
#pragma unroll
  for (int nt = 0; nt < 3; ++nt)
#pragma unroll
    for (int r = 0; r < 4; ++r) {
      float hn = (1.f - z[nt][r]) * ho[nt][r] + z[nt][r] * tanh_(ah[nt][r]);
      ho[nt][r] = hn;
      hT[(cg * 4 + r) * 72 + nt * 16 + cl] = f2u(hn);
      pout[r] += hn * wo[nt];
    }
  if (step >= 11) {
#pragma unroll
    for (int r = 0; r < 4; ++r) {
      float p = pout[r];
      p += __shfl_xor(p, 1);
      p += __shfl_xor(p, 2);
      p += __shfl_xor(p, 4);
      p += __shfl_xor(p, 8);
      if (cl == 0)
        sto(out, ((size_t)b * TP_ + (step - 11)) * N_ + n0 + cg * 4 + r, p + bo);
    }
  }
  if (PF) {
#pragma unroll
    for (int gn = 0; gn < 9; ++gn) cx[gn] = nx[gn];
  }
  asm volatile("" ::: "memory");
}

template <typename TI, typename TO>
__device__ __forceinline__ void gru8_body(
    unsigned short* hT, unsigned short* rhT,
    const unsigned short* xfrag, const unsigned short* pwb,
    const TI* Wout, const TI* bout, TO* out) {
  int l = threadIdx.x;          // 64
  int cg = l >> 4, cl = l & 15;
  int blk = blockIdx.x;
  int b = blk / 50;
  int n0 = (blk % 50) * 16;

  for (int e = l; e < 1152; e += 64) { hT[e] = 0; rhT[e] = 0; }
  float wo[3];
  float bo = ldc(bout, 0);
#pragma unroll
  for (int nt = 0; nt < 3; ++nt) wo[nt] = ldc(Wout, nt * 16 + cl);
  float ho[3][4];
#pragma unroll
  for (int nt = 0; nt < 3; ++nt)
#pragma unroll
    for (int r = 0; r < 4; ++r) ho[nt][r] = 0.f;

  const unsigned short* xg = xfrag + (size_t)blk * 21 * 2304;
  s8b WA_z[3][2], WA_r[3][2], WA_h[3][2];
  s8b WB_z[3][2], WB_r[3][2], WB_h[3][2];
  ushort4 cx[9];
  {
    const unsigned short* pb = pwb + (size_t)l * 8;
#pragma unroll
    for (int nt = 0; nt < 3; ++nt)
#pragma unroll
      for (int c = 0; c < 2; ++c) {
        WA_z[nt][c] = *(const s8b*)(pb + 0 * 9216 + nt * 3072 + c * 1536);
        WA_r[nt][c] = *(const s8b*)(pb + 1 * 9216 + nt * 3072 + c * 1536);
        WA_h[nt][c] = *(const s8b*)(pb + 2 * 9216 + nt * 3072 + c * 1536);
      }
#pragma unroll
    for (int gn = 0; gn < 9; ++gn)
      cx[gn] = *(const ushort4*)(xg + gn * 256 + l * 4);
  }
  asm volatile("" ::: "memory");

#pragma unroll 1
  for (int s2 = 0; s2 < 10; ++s2) {
    gru_step<true>(2 * s2, cl, cg, b, n0, WA_z, WA_r, WA_h, WB_z, WB_r, WB_h,
                   cx, xg, pwb, hT, rhT, ho, wo, bo, out);
    gru_step<true>(2 * s2 + 1, cl, cg, b, n0, WB_z, WB_r, WB_h, WA_z, WA_r, WA_h,
                   cx, xg, pwb, hT, rhT, ho, wo, bo, out);
  }
  gru_step<false>(20, cl, cg, b, n0, WA_z, WA_r, WA_h, WB_z, WB_r, WB_h,
                  cx, xg, pwb, hT, rhT, ho, wo, bo, out);
}
__global__ __launch_bounds__(64, 1) void k_gru8(
    const int* dtf, const bf16* xfrag, const bf16* pwb,
    const void* Wout, const void* bout, void* out) {
  __shared__ alignas(16) unsigned short hT[1152];    // [16][72]
  __shared__ alignas(16) unsigned short rhT[1152];
  if (*dtf)
    gru8_body<float, float>(hT, rhT,
                            (const unsigned short*)xfrag, (const unsigned short*)pwb,
                            (const float*)Wout, (const float*)bout, (float*)out);
  else
    gru8_body<bf16, bf16>(hT, rhT,
                          (const unsigned short*)xfrag, (const unsigned short*)pwb,
                          (const bf16*)Wout, (const bf16*)bout, (bf16*)out);
}

// ---------------------------------------------------------------------------
extern "C" void kernel_launch(void* const* d_in, const int* in_sizes, int n_in,
                              void* d_out, int out_size, void* d_ws, size_t ws_size,
                              hipStream_t stream) {
  (void)in_sizes; (void)n_in; (void)out_size; (void)ws_size;
  const void* x       = d_in[0];
  const void* T       = d_in[1];
  const void* Wq_t    = d_in[3];
  const void* Wk_t    = d_in[4];
  const void* Wv_t    = d_in[5];
  const void* Wq_st   = d_in[6];
  const void* Wk_st   = d_in[7];
  const void* Wv_st   = d_in[8];
  const void* bq_t    = d_in[9];
  const void* bk_t    = d_in[10];
  const void* bv_t    = d_in[11];
  const void* bq_st   = d_in[12];
  const void* bk_st   = d_in[13];
  const void* bv_st   = d_in[14];
  const void* conv1_w = d_in[15];
  const void* conv1_b = d_in[16];
  const void* Wproj_t = d_in[17];
  const void* bproj_t = d_in[18];
  const void* Wproj_st= d_in[19];
  const void* bproj_st= d_in[20];
  const void* xhr_wz  = d_in[21];
  const void* xhr_wr  = d_in[22];
  const void* xhr_wh  = d_in[23];
  const void* xhr_bz  = d_in[24];
  const void* xhr_br  = d_in[25];
  const void* xhr_bh  = d_in[26];
  const void* last_wz = d_in[27];
  const void* last_wr = d_in[28];
  const void* last_wh = d_in[29];
  const void* last_bz = d_in[30];
  const void* last_br = d_in[31];
  const void* last_bh = d_in[32];
  const void* Wout    = d_in[33];
  const void* bout    = d_in[34];

  // ws layout (~14.2 MB; proven safe earlier)
  char* wsb = (char*)d_ws;
  int* dtf     = (int*)wsb;                              // 256 B
  bf16* att_t  = (bf16*)(wsb + 256);                     // 2*11*800*48
  bf16* att_st = att_t + (size_t)2 * 11 * 800 * 48;
  bf16* xfrag  = att_st + (size_t)2 * 11 * 800 * 48;     // 100*21*9*64*4 elems
  bf16* pwb    = xfrag + (size_t)100 * 21 * 9 * 64 * 4;  // 21*27648

  k_detect<<<1, 64, 0, stream>>>((const unsigned int*)x, dtf);
  k_pack<<<(21 * 27648 + 255) / 256, 256, 0, stream>>>(
      dtf, xhr_wz, xhr_wr, xhr_wh, last_wz, last_wr, last_wh, pwb);
  {
    int total = B_ * (TIN_ - 1) * H_ * N_;
    k_temporal<<<(total + 255) / 256, 256, 0, stream>>>(
        dtf, x, Wq_t, Wk_t, Wv_t, bq_t, bk_t, bv_t, att_t);
  }
  k_spatial2<<<dim3(ST_TILES, 11, 2), 832, 0, stream>>>(
      dtf, x, Wq_st, Wk_st, Wv_st, bq_st, bk_st, bv_st, att_st);
  k_xparts<<<dim3(13, 21, 2), 192, 0, stream>>>(
      dtf, att_t, att_st, Wproj_t, bproj_t, Wproj_st, bproj_st,
      xhr_wz, xhr_wr, xhr_wh, xhr_bz, xhr_br, xhr_bh,
      x, T, conv1_w, conv1_b, last_wz, last_wr, last_wh,
      last_bz, last_br, last_bh, xfrag);
  k_gru8<<<100, 64, 0, stream>>>(
      dtf, xfrag, pwb, Wout, bout, d_out);
}